// Round 1
// baseline (4286.408 us; speedup 1.0000x reference)
//
#include <hip/hip_runtime.h>
#include <stdint.h>

// Problem constants (B=4, C=O=320, H=W=64, low=320, cat=640)
#define HW   4096
#define CH   320
#define CATC 640

// ws layout (floats):
//   h:      [0, 5242880)
//   dconv:  [5242880, 10485760)
//   Wcomb:  [10485760, 10690560)           (320*640)
//   oIdx (uint32): next 73728              (9*4096*2)
//   oW:     next 147456                    (9*4096*4)
// total ~41.6 MiB

// ---------------------------------------------------------------------------
// Precompute bilinear gather indices/weights per (k, pixel).
// Coordinates depend only on (k, i, j) — reused across all b, c.
__global__ __launch_bounds__(256) void k_off(const float* __restrict__ off,
                                             uint32_t* __restrict__ oIdx,
                                             float* __restrict__ oW)
{
    int gid = blockIdx.x * 256 + threadIdx.x;
    if (gid >= 9 * HW) return;
    int k = gid >> 12;
    int p = gid & 4095;
    int i = p >> 6, j = p & 63;
    float dy = off[(2 * k) * HW + p];
    float dx = off[(2 * k + 1) * HW + p];
    float py = (float)(i - 1 + k / 3) + dy;
    float px = (float)(j - 1 + k % 3) + dx;
    float fy = floorf(py), fx = floorf(px);
    float wy = py - fy, wx = px - fx;
    // clamp before int cast to avoid UB on weird values (validity handled below)
    fy = fminf(fmaxf(fy, -100.f), 100.f);
    fx = fminf(fmaxf(fx, -100.f), 100.f);
    int y0 = (int)fy, x0 = (int)fx;
    float vy0 = (y0 >= 0 && y0 < 64) ? 1.f : 0.f;
    float vy1 = (y0 >= -1 && y0 < 63) ? 1.f : 0.f;
    float vx0 = (x0 >= 0 && x0 < 64) ? 1.f : 0.f;
    float vx1 = (x0 >= -1 && x0 < 63) ? 1.f : 0.f;
    float w00 = (1.f - wy) * (1.f - wx) * vy0 * vx0;
    float w01 = (1.f - wy) * wx * vy0 * vx1;
    float w10 = wy * (1.f - wx) * vy1 * vx0;
    float w11 = wy * wx * vy1 * vx1;
    int ya = min(max(y0, 0), 63), yb = min(max(y0 + 1, 0), 63);
    int xa = min(max(x0, 0), 63), xb = min(max(x0 + 1, 0), 63);
    oIdx[gid * 2 + 0] = (uint32_t)(ya * 64 + xa) | ((uint32_t)(ya * 64 + xb) << 16);
    oIdx[gid * 2 + 1] = (uint32_t)(yb * 64 + xa) | ((uint32_t)(yb * 64 + xb) << 16);
    oW[gid * 4 + 0] = w00;
    oW[gid * 4 + 1] = w01;
    oW[gid * 4 + 2] = w10;
    oW[gid * 4 + 3] = w11;
}

// ---------------------------------------------------------------------------
// W_comb[o, c] = sum_l w_up[o, l] * w_down[l, c]   (320 x 640, K=320)
__global__ __launch_bounds__(256) void k_comb(const float* __restrict__ w_down,
                                              const float* __restrict__ w_up,
                                              float* __restrict__ Wc)
{
    int gid = blockIdx.x * 256 + threadIdx.x; // exactly 204800 threads
    int o = gid / CATC, c = gid % CATC;
    float acc = 0.f;
    for (int l = 0; l < 320; ++l)
        acc += w_up[o * 320 + l] * w_down[l * CATC + c];
    Wc[gid] = acc;
}

// ---------------------------------------------------------------------------
// Standard 3x3 conv, zero pad. Block: 16x16 pixel tile x 16 output channels.
// Thread: 4 o x 4 px accumulators (t = og*64 + pg; pg -> row=pg>>2, colgrp=pg&3).
__global__ __launch_bounds__(256) void k_conv(const float* __restrict__ x,
                                              const float* __restrict__ w,
                                              const float* __restrict__ bias,
                                              float* __restrict__ h)
{
    __shared__ float xs[18 * 18];
    __shared__ float wT[9 * 16];
    const int tile = blockIdx.x, oc0 = blockIdx.y * 16, b = blockIdx.z;
    const int ty0 = (tile >> 2) * 16, tx0 = (tile & 3) * 16;
    const int t = threadIdx.x;
    const int pg = t & 63, og = t >> 6;
    const int pr = pg >> 2, pc0 = (pg & 3) * 4;
    float acc[4][4] = {};
    const float* xb = x + (size_t)b * CH * HW;
    for (int c = 0; c < CH; ++c) {
        __syncthreads();
        for (int idx = t; idx < 324; idx += 256) {
            int r = idx / 18, cc = idx - r * 18;
            int gy = ty0 - 1 + r, gx = tx0 - 1 + cc;
            float v = 0.f;
            if ((unsigned)gy < 64u && (unsigned)gx < 64u)
                v = xb[c * HW + gy * 64 + gx];
            xs[idx] = v;
        }
        if (t < 144) {
            int o = t / 9, k = t - o * 9;
            wT[k * 16 + o] = w[((size_t)(oc0 + o) * CH + c) * 9 + k];
        }
        __syncthreads();
        float xr[3][6];
        #pragma unroll
        for (int di = 0; di < 3; ++di)
            #pragma unroll
            for (int u = 0; u < 6; ++u)
                xr[di][u] = xs[(pr + di) * 18 + pc0 + u];
        #pragma unroll
        for (int k = 0; k < 9; ++k) {
            const int di = k / 3, dj = k % 3;
            float4 wv = *(const float4*)&wT[k * 16 + og * 4];
            const float* wvp = (const float*)&wv;
            #pragma unroll
            for (int oo = 0; oo < 4; ++oo)
                #pragma unroll
                for (int px = 0; px < 4; ++px)
                    acc[oo][px] += wvp[oo] * xr[di][dj + px];
        }
    }
    #pragma unroll
    for (int oo = 0; oo < 4; ++oo) {
        int oabs = oc0 + og * 4 + oo;
        float bv = bias[oabs];
        float4 r;
        r.x = acc[oo][0] + bv;
        r.y = acc[oo][1] + bv;
        r.z = acc[oo][2] + bv;
        r.w = acc[oo][3] + bv;
        *(float4*)&h[((size_t)b * CH + oabs) * HW + (ty0 + pr) * 64 + tx0 + pc0] = r;
    }
}

// ---------------------------------------------------------------------------
// Deformable conv: per c, stage bilinear-sampled values (9 per pixel) to LDS,
// then same register-blocked multiply as k_conv.
__global__ __launch_bounds__(256) void k_dconv(const float* __restrict__ x,
                                               const float* __restrict__ w,
                                               const float* __restrict__ bias,
                                               const uint32_t* __restrict__ oIdx,
                                               const float* __restrict__ oW,
                                               float* __restrict__ dconv)
{
    __shared__ float ss[9 * 256];
    __shared__ float wT[9 * 16];
    const int tile = blockIdx.x, oc0 = blockIdx.y * 16, b = blockIdx.z;
    const int ty0 = (tile >> 2) * 16, tx0 = (tile & 3) * 16;
    const int t = threadIdx.x;
    const int pg = t & 63, og = t >> 6;
    const int pr = pg >> 2, pc0 = (pg & 3) * 4;
    // staging pixel for this thread (t in [0,256): row t>>4, col t&15)
    const int sgp = (ty0 + (t >> 4)) * 64 + tx0 + (t & 15);
    uint32_t pk0[9], pk1[9];
    float pw[9][4];
    #pragma unroll
    for (int k = 0; k < 9; ++k) {
        int gi = k * HW + sgp;
        pk0[k] = oIdx[gi * 2];
        pk1[k] = oIdx[gi * 2 + 1];
        float4 wv = *(const float4*)&oW[gi * 4];
        pw[k][0] = wv.x; pw[k][1] = wv.y; pw[k][2] = wv.z; pw[k][3] = wv.w;
    }
    float acc[4][4] = {};
    const float* xb = x + (size_t)b * CH * HW;
    for (int c = 0; c < CH; ++c) {
        __syncthreads();
        const float* xp = xb + c * HW;
        #pragma unroll
        for (int k = 0; k < 9; ++k) {
            float v = pw[k][0] * xp[pk0[k] & 0xFFFFu]
                    + pw[k][1] * xp[pk0[k] >> 16]
                    + pw[k][2] * xp[pk1[k] & 0xFFFFu]
                    + pw[k][3] * xp[pk1[k] >> 16];
            ss[k * 256 + t] = v;
        }
        if (t < 144) {
            int o = t / 9, k = t - o * 9;
            wT[k * 16 + o] = w[((size_t)(oc0 + o) * CH + c) * 9 + k];
        }
        __syncthreads();
        #pragma unroll
        for (int k = 0; k < 9; ++k) {
            float4 sv = *(const float4*)&ss[k * 256 + pr * 16 + pc0];
            float4 wv = *(const float4*)&wT[k * 16 + og * 4];
            const float* svp = (const float*)&sv;
            const float* wvp = (const float*)&wv;
            #pragma unroll
            for (int oo = 0; oo < 4; ++oo)
                #pragma unroll
                for (int px = 0; px < 4; ++px)
                    acc[oo][px] += wvp[oo] * svp[px];
        }
    }
    #pragma unroll
    for (int oo = 0; oo < 4; ++oo) {
        int oabs = oc0 + og * 4 + oo;
        float bv = bias[oabs];
        float4 r;
        r.x = acc[oo][0] + bv;
        r.y = acc[oo][1] + bv;
        r.z = acc[oo][2] + bv;
        r.w = acc[oo][3] + bv;
        *(float4*)&dconv[((size_t)b * CH + oabs) * HW + (ty0 + pr) * 64 + tx0 + pc0] = r;
    }
}

// ---------------------------------------------------------------------------
// out = h + scale * (W_comb @ [dconv; h])   (K=640 channel GEMM + residual)
__global__ __launch_bounds__(256) void k_final(const float* __restrict__ h,
                                               const float* __restrict__ dconv,
                                               const float* __restrict__ Wc,
                                               const float* __restrict__ scale_p,
                                               float* __restrict__ out)
{
    __shared__ float insl[4 * 256];
    __shared__ float wT2[4 * 16];
    const int tile = blockIdx.x, oc0 = blockIdx.y * 16, b = blockIdx.z;
    const int ty0 = (tile >> 2) * 16, tx0 = (tile & 3) * 16;
    const int t = threadIdx.x;
    const int pg = t & 63, og = t >> 6;
    const int pr = pg >> 2, pc0 = (pg & 3) * 4;
    const int sgp = (ty0 + (t >> 4)) * 64 + tx0 + (t & 15);
    float acc[4][4] = {};
    const size_t bbase = (size_t)b * CH * HW;
    for (int cc = 0; cc < CATC; cc += 4) {
        __syncthreads();
        #pragma unroll
        for (int u = 0; u < 4; ++u) {
            int ch = cc + u;
            const float* src = (ch < CH) ? (dconv + bbase + (size_t)ch * HW)
                                         : (h + bbase + (size_t)(ch - CH) * HW);
            insl[u * 256 + t] = src[sgp];
        }
        if (t < 64) {
            int u = t >> 4, o = t & 15;
            wT2[u * 16 + o] = Wc[(size_t)(oc0 + o) * CATC + cc + u];
        }
        __syncthreads();
        #pragma unroll
        for (int u = 0; u < 4; ++u) {
            float4 iv = *(const float4*)&insl[u * 256 + pr * 16 + pc0];
            float4 wv = *(const float4*)&wT2[u * 16 + og * 4];
            const float* ivp = (const float*)&iv;
            const float* wvp = (const float*)&wv;
            #pragma unroll
            for (int oo = 0; oo < 4; ++oo)
                #pragma unroll
                for (int px = 0; px < 4; ++px)
                    acc[oo][px] += wvp[oo] * ivp[px];
        }
    }
    float s = *scale_p;
    #pragma unroll
    for (int oo = 0; oo < 4; ++oo) {
        int oabs = oc0 + og * 4 + oo;
        size_t base = bbase + (size_t)oabs * HW + (ty0 + pr) * 64 + tx0 + pc0;
        float4 hv = *(const float4*)&h[base];
        float4 r;
        r.x = hv.x + s * acc[oo][0];
        r.y = hv.y + s * acc[oo][1];
        r.z = hv.z + s * acc[oo][2];
        r.w = hv.w + s * acc[oo][3];
        *(float4*)&out[base] = r;
    }
}

// ---------------------------------------------------------------------------
extern "C" void kernel_launch(void* const* d_in, const int* in_sizes, int n_in,
                              void* d_out, int out_size, void* d_ws, size_t ws_size,
                              hipStream_t stream)
{
    const float* x      = (const float*)d_in[0];
    const float* weight = (const float*)d_in[1];
    const float* bias   = (const float*)d_in[2];
    const float* w_down = (const float*)d_in[3];
    const float* w_up   = (const float*)d_in[4];
    const float* scale  = (const float*)d_in[5];
    const float* offset = (const float*)d_in[6];
    float* ws = (float*)d_ws;
    float* h     = ws;
    float* dconv = ws + 5242880;
    float* Wc    = ws + 10485760;
    uint32_t* oIdx = (uint32_t*)(ws + 10690560);
    float* oW    = ws + 10690560 + 73728;
    float* outf  = (float*)d_out;

    hipLaunchKernelGGL(k_off,  dim3(144), dim3(256), 0, stream, offset, oIdx, oW);
    hipLaunchKernelGGL(k_comb, dim3(800), dim3(256), 0, stream, w_down, w_up, Wc);
    hipLaunchKernelGGL(k_conv, dim3(16, 20, 4), dim3(256), 0, stream, x, weight, bias, h);
    hipLaunchKernelGGL(k_dconv, dim3(16, 20, 4), dim3(256), 0, stream,
                       x, weight, bias, oIdx, oW, dconv);
    hipLaunchKernelGGL(k_final, dim3(16, 20, 4), dim3(256), 0, stream,
                       h, dconv, Wc, scale, outf);
}

// Round 3
// 635.865 us; speedup vs baseline: 6.7411x; 6.7411x over previous
//
#include <hip/hip_runtime.h>
#include <stdint.h>

// Problem: B=4, C=O=320, H=W=64 -> HW=4096, N=B*HW=16384, K=2880, Kf=640.
// K-permutation: kk = g*72 + k*8 + cl, where c = g*8+cl (g<40, k<9, cl<8).
// S packed-8 layout: elem(kk,n) at ushort index (kkb*16384+n)*8 + (kk&7), kkb=kk>>3.
// C buffers (dconv/h) packed-8 along o: elem(o,n) at (o>>3)*16384*8 + n*8 + (o&7).

#define NTOT 16384

typedef __attribute__((ext_vector_type(4))) float f32x4;
typedef __attribute__((ext_vector_type(8))) short bf16x8;

typedef __attribute__((address_space(1))) const unsigned int uint_as1;
typedef __attribute__((address_space(3))) unsigned int uint_as3;

__device__ __forceinline__ void gl_lds16(const void* g, void* l) {
    __builtin_amdgcn_global_load_lds((uint_as1*)g, (uint_as3*)l, 16, 0, 0);
}

__device__ __forceinline__ unsigned short f2b(float f) {
    union { float f; uint32_t u; } v; v.f = f;
    uint32_t r = (v.u + 0x7FFFu + ((v.u >> 16) & 1u)) >> 16;
    return (unsigned short)r;
}
__device__ __forceinline__ float b2f(unsigned short h) {
    union { uint32_t u; float f; } v; v.u = ((uint32_t)h) << 16;
    return v.f;
}

// ---------------------------------------------------------------------------
// Bilinear tables per (k, pixel) — identical to round-1 (verified).
__global__ __launch_bounds__(256) void k_off(const float* __restrict__ off,
                                             uint32_t* __restrict__ oIdx,
                                             float* __restrict__ oW)
{
    int gid = blockIdx.x * 256 + threadIdx.x;
    if (gid >= 9 * 4096) return;
    int k = gid >> 12;
    int p = gid & 4095;
    int i = p >> 6, j = p & 63;
    float dy = off[(2 * k) * 4096 + p];
    float dx = off[(2 * k + 1) * 4096 + p];
    float py = (float)(i - 1 + k / 3) + dy;
    float px = (float)(j - 1 + k % 3) + dx;
    float fy = floorf(py), fx = floorf(px);
    float wy = py - fy, wx = px - fx;
    fy = fminf(fmaxf(fy, -100.f), 100.f);
    fx = fminf(fmaxf(fx, -100.f), 100.f);
    int y0 = (int)fy, x0 = (int)fx;
    float vy0 = (y0 >= 0 && y0 < 64) ? 1.f : 0.f;
    float vy1 = (y0 >= -1 && y0 < 63) ? 1.f : 0.f;
    float vx0 = (x0 >= 0 && x0 < 64) ? 1.f : 0.f;
    float vx1 = (x0 >= -1 && x0 < 63) ? 1.f : 0.f;
    float w00 = (1.f - wy) * (1.f - wx) * vy0 * vx0;
    float w01 = (1.f - wy) * wx * vy0 * vx1;
    float w10 = wy * (1.f - wx) * vy1 * vx0;
    float w11 = wy * wx * vy1 * vx1;
    int ya = min(max(y0, 0), 63), yb = min(max(y0 + 1, 0), 63);
    int xa = min(max(x0, 0), 63), xb = min(max(x0 + 1, 0), 63);
    oIdx[gid * 2 + 0] = (uint32_t)(ya * 64 + xa) | ((uint32_t)(ya * 64 + xb) << 16);
    oIdx[gid * 2 + 1] = (uint32_t)(yb * 64 + xa) | ((uint32_t)(yb * 64 + xb) << 16);
    oW[gid * 4 + 0] = w00;
    oW[gid * 4 + 1] = w01;
    oW[gid * 4 + 2] = w10;
    oW[gid * 4 + 3] = w11;
}

// ---------------------------------------------------------------------------
// Pack conv weight into bf16, K-permuted, M padded to 384.
__global__ __launch_bounds__(256) void k_packW(const float* __restrict__ w,
                                               unsigned short* __restrict__ Wr)
{
    int gid = blockIdx.x * 256 + threadIdx.x;   // 384*2880 = 1105920
    if (gid >= 384 * 2880) return;
    int o = gid / 2880, kk = gid % 2880;
    int g = kk / 72, r = kk % 72, k = r >> 3, cl = r & 7, c = g * 8 + cl;
    float v = (o < 320) ? w[((size_t)o * 320 + c) * 9 + k] : 0.f;
    Wr[gid] = f2b(v);
}

// ---------------------------------------------------------------------------
// W2[o, c2] = sum_l w_up[o,l] * w_down[l,c2], bf16, M padded to 384.
__global__ __launch_bounds__(128) void k_comb2(const float* __restrict__ wd,
                                               const float* __restrict__ wu,
                                               unsigned short* __restrict__ W2)
{
    int kk2 = blockIdx.x * 128 + threadIdx.x;   // 640
    int o = blockIdx.y;                          // 384
    float acc = 0.f;
    if (o < 320) {
        for (int l = 0; l < 320; ++l)
            acc += wu[o * 320 + l] * wd[l * 640 + kk2];
    }
    W2[o * 640 + kk2] = f2b(acc);
}

// ---------------------------------------------------------------------------
// Gather: build S chunk (32 c = 4 groups, K=288) for all b, n. mode 0 =
// bilinear (dconv), mode 1 = identity shift w/ zero pad (conv im2col).
// Block: (split 16, gl 4, b 4); stages 8 full bf16 x-planes in LDS.
__global__ __launch_bounds__(256) void k_gather(const float* __restrict__ x,
                                                const uint32_t* __restrict__ oIdx,
                                                const float* __restrict__ oW,
                                                unsigned short* __restrict__ Sp,
                                                int c_base, int mode)
{
    __shared__ __align__(16) unsigned short pl[8 * 4096];
    const int tid = threadIdx.x;
    const int split = blockIdx.x, gl = blockIdx.y, b = blockIdx.z;
    const int c0 = c_base + gl * 8;
    const float* xb = x + ((size_t)b * 320 + c0) * 4096;
    // 8 planes * 1024 float4-units/plane = 8192 units; 256 thr -> 32 iters.
    #pragma unroll 4
    for (int i = 0; i < 32; ++i) {
        int u = tid + i * 256;
        int cl = u >> 10, p4 = (u & 1023) * 4;
        float4 v = *(const float4*)(xb + (size_t)cl * 4096 + p4);
        ushort4 sv;
        sv.x = f2b(v.x); sv.y = f2b(v.y); sv.z = f2b(v.z); sv.w = f2b(v.w);
        *(ushort4*)&pl[cl * 4096 + p4] = sv;
    }
    __syncthreads();
    const int px = split * 256 + tid;
    const int n = b * 4096 + px;
    if (mode == 0) {
        #pragma unroll
        for (int k = 0; k < 9; ++k) {
            int gi = k * 4096 + px;
            uint32_t i0 = oIdx[gi * 2], i1 = oIdx[gi * 2 + 1];
            float4 w = *(const float4*)&oW[gi * 4];
            int t00 = i0 & 0xFFFF, t01 = i0 >> 16;
            int t10 = i1 & 0xFFFF, t11 = i1 >> 16;
            uint32_t pk[4];
            #pragma unroll
            for (int q = 0; q < 4; ++q) {
                const unsigned short* Pa = pl + (q * 2) * 4096;
                const unsigned short* Pb = pl + (q * 2 + 1) * 4096;
                float va = w.x * b2f(Pa[t00]) + w.y * b2f(Pa[t01])
                         + w.z * b2f(Pa[t10]) + w.w * b2f(Pa[t11]);
                float vb = w.x * b2f(Pb[t00]) + w.y * b2f(Pb[t01])
                         + w.z * b2f(Pb[t10]) + w.w * b2f(Pb[t11]);
                pk[q] = (uint32_t)f2b(va) | ((uint32_t)f2b(vb) << 16);
            }
            int4 st; st.x = pk[0]; st.y = pk[1]; st.z = pk[2]; st.w = pk[3];
            *(int4*)(Sp + ((size_t)(gl * 9 + k) * NTOT + n) * 8) = st;
        }
    } else {
        int row = px >> 6, col = px & 63;
        #pragma unroll
        for (int k = 0; k < 9; ++k) {
            int di = k / 3 - 1, dj = k % 3 - 1;
            bool ok = ((unsigned)(row + di) < 64u) && ((unsigned)(col + dj) < 64u);
            int idx = px + di * 64 + dj;
            uint32_t pk[4];
            #pragma unroll
            for (int q = 0; q < 4; ++q) {
                unsigned short a = ok ? pl[(q * 2) * 4096 + idx] : (unsigned short)0;
                unsigned short bq = ok ? pl[(q * 2 + 1) * 4096 + idx] : (unsigned short)0;
                pk[q] = (uint32_t)a | ((uint32_t)bq << 16);
            }
            int4 st; st.x = pk[0]; st.y = pk[1]; st.z = pk[2]; st.w = pk[3];
            *(int4*)(Sp + ((size_t)(gl * 9 + k) * NTOT + n) * 8) = st;
        }
    }
}

// ---------------------------------------------------------------------------
// MFMA GEMM pass: C[o,n] (+)= Wr[:, kk0:kk0+288] x S. BM=BN=128, BK=32,
// 256 threads, 4 waves 2x2 (wave tile 64x64, 16 accs). C packed-8 bf16 RMW.
__global__ __launch_bounds__(256) void k_gemm(const unsigned short* __restrict__ Sp,
                                              const unsigned short* __restrict__ Wr,
                                              unsigned short* __restrict__ Cbuf,
                                              const float* __restrict__ bias,
                                              int first, int kk0)
{
    __shared__ __align__(16) unsigned short As[128 * 32];
    __shared__ __align__(16) unsigned short Bs[32 * 128];
    const int tid = threadIdx.x;
    const int n0 = blockIdx.x * 128, m0 = blockIdx.y * 128;
    const int lane = tid & 63, w = tid >> 6;
    const int wm = w & 1, wn = w >> 1;
    const int quad = lane >> 4, nl = lane & 15;
    f32x4 acc[4][4];
    #pragma unroll
    for (int mt = 0; mt < 4; ++mt)
        #pragma unroll
        for (int nt = 0; nt < 4; ++nt)
            acc[mt][nt] = 0.f;

    for (int s = 0; s < 9; ++s) {
        __syncthreads();
        #pragma unroll
        for (int q = 0; q < 2; ++q) {
            int u = tid + q * 256;
            int m = u >> 2, qq = u & 3;
            gl_lds16(Wr + (size_t)(m0 + m) * 2880 + kk0 + s * 32 + qq * 8, &As[u * 8]);
        }
        #pragma unroll
        for (int q = 0; q < 2; ++q) {
            int u = tid + q * 256;
            int kkb = u >> 7, nn = n0 + (u & 127);
            gl_lds16(Sp + ((size_t)(s * 4 + kkb) * NTOT + nn) * 8, &Bs[u * 8]);
        }
        __syncthreads();
        bf16x8 a[4], b[4];
        #pragma unroll
        for (int mt = 0; mt < 4; ++mt)
            a[mt] = *(const bf16x8*)&As[(wm * 64 + mt * 16 + nl) * 32 + quad * 8];
        #pragma unroll
        for (int nt = 0; nt < 4; ++nt)
            b[nt] = *(const bf16x8*)&Bs[(quad * 128 + wn * 64 + nt * 16 + nl) * 8];
        #pragma unroll
        for (int mt = 0; mt < 4; ++mt)
            #pragma unroll
            for (int nt = 0; nt < 4; ++nt)
                acc[mt][nt] = __builtin_amdgcn_mfma_f32_16x16x32_bf16(a[mt], b[nt], acc[mt][nt], 0, 0, 0);
    }

    #pragma unroll
    for (int mt = 0; mt < 4; ++mt) {
        int o0 = m0 + wm * 64 + mt * 16 + quad * 4;
        #pragma unroll
        for (int nt = 0; nt < 4; ++nt) {
            int n = n0 + wn * 64 + nt * 16 + nl;
            unsigned short* p = Cbuf + ((size_t)(o0 >> 3) * NTOT + n) * 8 + (o0 & 7);
            float v0, v1, v2, v3;
            if (first) {
                v0 = acc[mt][nt][0] + ((o0 + 0 < 320) ? bias[o0 + 0] : 0.f);
                v1 = acc[mt][nt][1] + ((o0 + 1 < 320) ? bias[o0 + 1] : 0.f);
                v2 = acc[mt][nt][2] + ((o0 + 2 < 320) ? bias[o0 + 2] : 0.f);
                v3 = acc[mt][nt][3] + ((o0 + 3 < 320) ? bias[o0 + 3] : 0.f);
            } else {
                ushort4 old = *(const ushort4*)p;
                v0 = acc[mt][nt][0] + b2f(old.x);
                v1 = acc[mt][nt][1] + b2f(old.y);
                v2 = acc[mt][nt][2] + b2f(old.z);
                v3 = acc[mt][nt][3] + b2f(old.w);
            }
            ushort4 st;
            st.x = f2b(v0); st.y = f2b(v1); st.z = f2b(v2); st.w = f2b(v3);
            *(ushort4*)p = st;
        }
    }
}

// ---------------------------------------------------------------------------
// Final: out = h + scale * (W2 x cat), cat = [dconv(0:320); h(0:320)], K=640.
__global__ __launch_bounds__(256) void k_final(const unsigned short* __restrict__ W2,
                                               const unsigned short* __restrict__ Cd,
                                               const unsigned short* __restrict__ Ch,
                                               const float* __restrict__ scale,
                                               float* __restrict__ out)
{
    __shared__ __align__(16) unsigned short As[128 * 32];
    __shared__ __align__(16) unsigned short Bs[32 * 128];
    const int tid = threadIdx.x;
    const int n0 = blockIdx.x * 128, m0 = blockIdx.y * 128;
    const int lane = tid & 63, w = tid >> 6;
    const int wm = w & 1, wn = w >> 1;
    const int quad = lane >> 4, nl = lane & 15;
    f32x4 acc[4][4];
    #pragma unroll
    for (int mt = 0; mt < 4; ++mt)
        #pragma unroll
        for (int nt = 0; nt < 4; ++nt)
            acc[mt][nt] = 0.f;

    for (int s = 0; s < 20; ++s) {
        __syncthreads();
        #pragma unroll
        for (int q = 0; q < 2; ++q) {
            int u = tid + q * 256;
            int m = u >> 2, qq = u & 3;
            gl_lds16(W2 + (size_t)(m0 + m) * 640 + s * 32 + qq * 8, &As[u * 8]);
        }
        const unsigned short* src = (s < 10) ? Cd : Ch;
        int gq = (s < 10) ? s * 4 : (s - 10) * 4;
        #pragma unroll
        for (int q = 0; q < 2; ++q) {
            int u = tid + q * 256;
            int kkb = u >> 7, nn = n0 + (u & 127);
            gl_lds16(src + ((size_t)(gq + kkb) * NTOT + nn) * 8, &Bs[u * 8]);
        }
        __syncthreads();
        bf16x8 a[4], b[4];
        #pragma unroll
        for (int mt = 0; mt < 4; ++mt)
            a[mt] = *(const bf16x8*)&As[(wm * 64 + mt * 16 + nl) * 32 + quad * 8];
        #pragma unroll
        for (int nt = 0; nt < 4; ++nt)
            b[nt] = *(const bf16x8*)&Bs[(quad * 128 + wn * 64 + nt * 16 + nl) * 8];
        #pragma unroll
        for (int mt = 0; mt < 4; ++mt)
            #pragma unroll
            for (int nt = 0; nt < 4; ++nt)
                acc[mt][nt] = __builtin_amdgcn_mfma_f32_16x16x32_bf16(a[mt], b[nt], acc[mt][nt], 0, 0, 0);
    }

    float sc = scale[0];
    #pragma unroll
    for (int mt = 0; mt < 4; ++mt) {
        int o0 = m0 + wm * 64 + mt * 16 + quad * 4;
        if (o0 >= 320) continue;
        #pragma unroll
        for (int nt = 0; nt < 4; ++nt) {
            int n = n0 + wn * 64 + nt * 16 + nl;
            int b = n >> 12, px = n & 4095;
            ushort4 hv = *(const ushort4*)(Ch + ((size_t)(o0 >> 3) * NTOT + n) * 8 + (o0 & 7));
            size_t base = ((size_t)(b * 320 + o0)) * 4096 + px;
            out[base]            = b2f(hv.x) + sc * acc[mt][nt][0];
            out[base + 4096]     = b2f(hv.y) + sc * acc[mt][nt][1];
            out[base + 2 * 4096] = b2f(hv.z) + sc * acc[mt][nt][2];
            out[base + 3 * 4096] = b2f(hv.w) + sc * acc[mt][nt][3];
        }
    }
}

// ---------------------------------------------------------------------------
extern "C" void kernel_launch(void* const* d_in, const int* in_sizes, int n_in,
                              void* d_out, int out_size, void* d_ws, size_t ws_size,
                              hipStream_t stream)
{
    const float* x      = (const float*)d_in[0];
    const float* weight = (const float*)d_in[1];
    const float* bias   = (const float*)d_in[2];
    const float* w_down = (const float*)d_in[3];
    const float* w_up   = (const float*)d_in[4];
    const float* scale  = (const float*)d_in[5];
    const float* offset = (const float*)d_in[6];
    char* ws = (char*)d_ws;
    unsigned short* Sp = (unsigned short*)(ws + 0);          //  9,437,184 B
    unsigned short* Cd = (unsigned short*)(ws + 9437184);    // 12,582,912 B
    unsigned short* Ch = (unsigned short*)(ws + 22020096);   // 12,582,912 B
    unsigned short* Wr = (unsigned short*)(ws + 34603008);   //  2,211,840 B
    unsigned short* W2 = (unsigned short*)(ws + 36814848);   //    491,520 B
    uint32_t*       oI = (uint32_t*)(ws + 37306368);         //    294,912 B
    float*          oW = (float*)(ws + 37601280);            //    589,824 B  (end 38.2 MB)
    float* out = (float*)d_out;

    hipLaunchKernelGGL(k_off,   dim3(144), dim3(256), 0, stream, offset, oI, oW);
    hipLaunchKernelGGL(k_packW, dim3(4320), dim3(256), 0, stream, weight, Wr);
    hipLaunchKernelGGL(k_comb2, dim3(5, 384), dim3(128), 0, stream, w_down, w_up, W2);

    for (int pass = 0; pass < 10; ++pass) {
        hipLaunchKernelGGL(k_gather, dim3(16, 4, 4), dim3(256), 0, stream,
                           x, oI, oW, Sp, pass * 32, 0);
        hipLaunchKernelGGL(k_gemm, dim3(128, 3), dim3(256), 0, stream,
                           Sp, Wr, Cd, bias, pass == 0 ? 1 : 0, pass * 288);
    }
    for (int pass = 0; pass < 10; ++pass) {
        hipLaunchKernelGGL(k_gather, dim3(16, 4, 4), dim3(256), 0, stream,
                           x, oI, oW, Sp, pass * 32, 1);
        hipLaunchKernelGGL(k_gemm, dim3(128, 3), dim3(256), 0, stream,
                           Sp, Wr, Ch, bias, pass == 0 ? 1 : 0, pass * 288);
    }
    hipLaunchKernelGGL(k_final, dim3(128, 3), dim3(256), 0, stream,
                       W2, Cd, Ch, scale, out);
}

// Round 4
// 370.581 us; speedup vs baseline: 11.5667x; 1.7159x over previous
//
#include <hip/hip_runtime.h>
#include <stdint.h>

// B=4, C=O=320, H=W=64 -> HW=4096, N=16384, K=2880 (M padded to 384), Kf=640.
// K-permutation: kk = g*72 + k*8 + cl, c = g*8+cl (g<40, k<9, cl<8).
// S packed-8: elem(kk,n) at ushort idx (kkb*16384+n)*8 + (kk&7), kkb=kk>>3.
// C buffers packed-8 along o: elem(o,n) at (o>>3)*16384*8 + n*8 + (o&7).
//
// ws layout (bytes):
//   Cd 0 .. 12,582,912 | Ch .. 25,165,824 | Wr .. 27,377,664 | W2 .. 27,869,184
//   oI .. 28,164,096 | oW .. 28,753,920 | Sp .. +cg*9*16384*16
// Tier A (cg=40, 1 pass/mode, reg-acc full K): needs 123,125,760 B
// Tier B (cg=8, 5 passes):                     needs  47,628,288 B
// Tier C (cg=4, 10 passes, round-3-proven):    needs  38,191,104 B

#define NTOT 16384

typedef __attribute__((ext_vector_type(4))) float f32x4;
typedef __attribute__((ext_vector_type(8))) short bf16x8;

typedef __attribute__((address_space(1))) const unsigned int uint_as1;
typedef __attribute__((address_space(3))) unsigned int uint_as3;

__device__ __forceinline__ void gl_lds16(const void* g, void* l) {
    __builtin_amdgcn_global_load_lds((uint_as1*)g, (uint_as3*)l, 16, 0, 0);
}

__device__ __forceinline__ unsigned short f2b(float f) {
    union { float f; uint32_t u; } v; v.f = f;
    uint32_t r = (v.u + 0x7FFFu + ((v.u >> 16) & 1u)) >> 16;
    return (unsigned short)r;
}
__device__ __forceinline__ float b2f(unsigned short h) {
    union { uint32_t u; float f; } v; v.u = ((uint32_t)h) << 16;
    return v.f;
}
__device__ __forceinline__ float b2f_lo(uint32_t u) {
    union { uint32_t u; float f; } v; v.u = u << 16;
    return v.f;
}
__device__ __forceinline__ float b2f_hi(uint32_t u) {
    union { uint32_t u; float f; } v; v.u = u & 0xFFFF0000u;
    return v.f;
}
__device__ __forceinline__ uint32_t pack2(float lo, float hi) {
    return (uint32_t)f2b(lo) | ((uint32_t)f2b(hi) << 16);
}

// ---------------------------------------------------------------------------
// Bilinear tables per (k, pixel) — verified in rounds 1/3.
__global__ __launch_bounds__(256) void k_off(const float* __restrict__ off,
                                             uint32_t* __restrict__ oIdx,
                                             float* __restrict__ oW)
{
    int gid = blockIdx.x * 256 + threadIdx.x;
    if (gid >= 9 * 4096) return;
    int k = gid >> 12;
    int p = gid & 4095;
    int i = p >> 6, j = p & 63;
    float dy = off[(2 * k) * 4096 + p];
    float dx = off[(2 * k + 1) * 4096 + p];
    float py = (float)(i - 1 + k / 3) + dy;
    float px = (float)(j - 1 + k % 3) + dx;
    float fy = floorf(py), fx = floorf(px);
    float wy = py - fy, wx = px - fx;
    fy = fminf(fmaxf(fy, -100.f), 100.f);
    fx = fminf(fmaxf(fx, -100.f), 100.f);
    int y0 = (int)fy, x0 = (int)fx;
    float vy0 = (y0 >= 0 && y0 < 64) ? 1.f : 0.f;
    float vy1 = (y0 >= -1 && y0 < 63) ? 1.f : 0.f;
    float vx0 = (x0 >= 0 && x0 < 64) ? 1.f : 0.f;
    float vx1 = (x0 >= -1 && x0 < 63) ? 1.f : 0.f;
    float w00 = (1.f - wy) * (1.f - wx) * vy0 * vx0;
    float w01 = (1.f - wy) * wx * vy0 * vx1;
    float w10 = wy * (1.f - wx) * vy1 * vx0;
    float w11 = wy * wx * vy1 * vx1;
    int ya = min(max(y0, 0), 63), yb = min(max(y0 + 1, 0), 63);
    int xa = min(max(x0, 0), 63), xb = min(max(x0 + 1, 0), 63);
    oIdx[gid * 2 + 0] = (uint32_t)(ya * 64 + xa) | ((uint32_t)(ya * 64 + xb) << 16);
    oIdx[gid * 2 + 1] = (uint32_t)(yb * 64 + xa) | ((uint32_t)(yb * 64 + xb) << 16);
    oW[gid * 4 + 0] = w00;
    oW[gid * 4 + 1] = w01;
    oW[gid * 4 + 2] = w10;
    oW[gid * 4 + 3] = w11;
}

// ---------------------------------------------------------------------------
__global__ __launch_bounds__(256) void k_packW(const float* __restrict__ w,
                                               unsigned short* __restrict__ Wr)
{
    int gid = blockIdx.x * 256 + threadIdx.x;   // 384*2880
    if (gid >= 384 * 2880) return;
    int o = gid / 2880, kk = gid % 2880;
    int g = kk / 72, r = kk % 72, k = r >> 3, cl = r & 7, c = g * 8 + cl;
    float v = (o < 320) ? w[((size_t)o * 320 + c) * 9 + k] : 0.f;
    Wr[gid] = f2b(v);
}

// ---------------------------------------------------------------------------
__global__ __launch_bounds__(128) void k_comb2(const float* __restrict__ wd,
                                               const float* __restrict__ wu,
                                               unsigned short* __restrict__ W2)
{
    int kk2 = blockIdx.x * 128 + threadIdx.x;   // 640
    int o = blockIdx.y;                          // 384
    float acc = 0.f;
    if (o < 320) {
        for (int l = 0; l < 320; ++l)
            acc += wu[o * 320 + l] * wd[l * 640 + kk2];
    }
    W2[o * 640 + kk2] = f2b(acc);
}

// ---------------------------------------------------------------------------
// Gather: one block = (1024 px) x (8 channels of group gl) x batch b.
// LDS: channel-interleaved pl32[px][pair] (pair p holds ch 2p | 2p+1<<16).
// One ds_read_b128 per tap yields all 8 channels.
__global__ __launch_bounds__(256) void k_gather(const float* __restrict__ x,
                                                const uint32_t* __restrict__ oIdx,
                                                const float* __restrict__ oW,
                                                unsigned short* __restrict__ Sp,
                                                int c_base, int mode)
{
    __shared__ __align__(16) uint32_t pl32[4096 * 4];   // 64 KB
    const int tid = threadIdx.x;
    const int split = blockIdx.x, gl = blockIdx.y, b = blockIdx.z;
    const int c0 = c_base + gl * 8;
    const float* xb = x + ((size_t)b * 320 + c0) * 4096;
    // stage: 16384 pair-dwords; lane pattern p=u&3, px=u>>2 -> LDS writes land
    // on 64 consecutive dwords per wave (conflict-free).
    #pragma unroll 8
    for (int it = 0; it < 64; ++it) {
        int u = it * 256 + tid;
        int p = u & 3, px = u >> 2;
        float va = xb[(size_t)(2 * p) * 4096 + px];
        float vb = xb[(size_t)(2 * p + 1) * 4096 + px];
        pl32[px * 4 + p] = pack2(va, vb);
    }
    __syncthreads();

    for (int i = 0; i < 4; ++i) {
        int px = split * 1024 + i * 256 + tid;
        int n = b * 4096 + px;
        if (mode == 0) {
            #pragma unroll
            for (int k = 0; k < 9; ++k) {
                int gi = k * 4096 + px;
                uint32_t i0 = oIdx[gi * 2], i1 = oIdx[gi * 2 + 1];
                float4 w = *(const float4*)&oW[gi * 4];
                int4 t0 = *(const int4*)&pl32[(i0 & 0xFFFFu) * 4];
                int4 t1 = *(const int4*)&pl32[(i0 >> 16) * 4];
                int4 t2 = *(const int4*)&pl32[(i1 & 0xFFFFu) * 4];
                int4 t3 = *(const int4*)&pl32[(i1 >> 16) * 4];
                float ac[8];
                #pragma unroll
                for (int q = 0; q < 8; ++q) ac[q] = 0.f;
#define TAP(tv, wv) \
    ac[0] += wv * b2f_lo((uint32_t)tv.x); ac[1] += wv * b2f_hi((uint32_t)tv.x); \
    ac[2] += wv * b2f_lo((uint32_t)tv.y); ac[3] += wv * b2f_hi((uint32_t)tv.y); \
    ac[4] += wv * b2f_lo((uint32_t)tv.z); ac[5] += wv * b2f_hi((uint32_t)tv.z); \
    ac[6] += wv * b2f_lo((uint32_t)tv.w); ac[7] += wv * b2f_hi((uint32_t)tv.w);
                TAP(t0, w.x) TAP(t1, w.y) TAP(t2, w.z) TAP(t3, w.w)
#undef TAP
                int4 st;
                st.x = (int)pack2(ac[0], ac[1]);
                st.y = (int)pack2(ac[2], ac[3]);
                st.z = (int)pack2(ac[4], ac[5]);
                st.w = (int)pack2(ac[6], ac[7]);
                *(int4*)(Sp + ((size_t)(gl * 9 + k) * NTOT + n) * 8) = st;
            }
        } else {
            int row = px >> 6, col = px & 63;
            #pragma unroll
            for (int k = 0; k < 9; ++k) {
                int di = k / 3 - 1, dj = k % 3 - 1;
                bool ok = ((unsigned)(row + di) < 64u) && ((unsigned)(col + dj) < 64u);
                int idx = px + di * 64 + dj;
                int4 st = {0, 0, 0, 0};
                if (ok) st = *(const int4*)&pl32[idx * 4];
                *(int4*)(Sp + ((size_t)(gl * 9 + k) * NTOT + n) * 8) = st;
            }
        }
    }
}

// ---------------------------------------------------------------------------
// MFMA GEMM: C[o,n] (+)= Wr[:, kk0 : kk0+s_steps*32] x S.
// BM=192, BN=128, BK=32; 4 waves 2x2 (wave tile 96x64 -> 6x4 accs).
__global__ __launch_bounds__(256) void k_gemm(const unsigned short* __restrict__ Sp,
                                              const unsigned short* __restrict__ Wr,
                                              unsigned short* __restrict__ Cbuf,
                                              const float* __restrict__ bias,
                                              int first, int kk0, int s_steps)
{
    __shared__ __align__(16) unsigned short As[192 * 32];
    __shared__ __align__(16) unsigned short Bs[32 * 128];
    const int tid = threadIdx.x;
    const int n0 = blockIdx.x * 128, m0 = blockIdx.y * 192;
    const int lane = tid & 63, w = tid >> 6;
    const int wm = w & 1, wn = w >> 1;
    const int quad = lane >> 4, nl = lane & 15;
    f32x4 acc[6][4];
    #pragma unroll
    for (int mt = 0; mt < 6; ++mt)
        #pragma unroll
        for (int nt = 0; nt < 4; ++nt)
            acc[mt][nt] = 0.f;

    for (int s = 0; s < s_steps; ++s) {
        __syncthreads();
        #pragma unroll
        for (int q = 0; q < 3; ++q) {
            int u = tid + q * 256;
            int m = u >> 2, qq = u & 3;
            gl_lds16(Wr + (size_t)(m0 + m) * 2880 + kk0 + s * 32 + qq * 8, &As[u * 8]);
        }
        #pragma unroll
        for (int q = 0; q < 2; ++q) {
            int u = tid + q * 256;
            int kkb = u >> 7, nn = n0 + (u & 127);
            gl_lds16(Sp + ((size_t)(s * 4 + kkb) * NTOT + nn) * 8, &Bs[u * 8]);
        }
        __syncthreads();
        bf16x8 a[6], bf[4];
        #pragma unroll
        for (int mt = 0; mt < 6; ++mt)
            a[mt] = *(const bf16x8*)&As[(wm * 96 + mt * 16 + nl) * 32 + quad * 8];
        #pragma unroll
        for (int nt = 0; nt < 4; ++nt)
            bf[nt] = *(const bf16x8*)&Bs[(quad * 128 + wn * 64 + nt * 16 + nl) * 8];
        #pragma unroll
        for (int mt = 0; mt < 6; ++mt)
            #pragma unroll
            for (int nt = 0; nt < 4; ++nt)
                acc[mt][nt] = __builtin_amdgcn_mfma_f32_16x16x32_bf16(a[mt], bf[nt], acc[mt][nt], 0, 0, 0);
    }

    #pragma unroll
    for (int mt = 0; mt < 6; ++mt) {
        int o0 = m0 + wm * 96 + mt * 16 + quad * 4;
        #pragma unroll
        for (int nt = 0; nt < 4; ++nt) {
            int n = n0 + wn * 64 + nt * 16 + nl;
            unsigned short* p = Cbuf + ((size_t)(o0 >> 3) * NTOT + n) * 8 + (o0 & 7);
            float v0, v1, v2, v3;
            if (first) {
                v0 = acc[mt][nt][0] + ((o0 + 0 < 320) ? bias[o0 + 0] : 0.f);
                v1 = acc[mt][nt][1] + ((o0 + 1 < 320) ? bias[o0 + 1] : 0.f);
                v2 = acc[mt][nt][2] + ((o0 + 2 < 320) ? bias[o0 + 2] : 0.f);
                v3 = acc[mt][nt][3] + ((o0 + 3 < 320) ? bias[o0 + 3] : 0.f);
            } else {
                ushort4 old = *(const ushort4*)p;
                v0 = acc[mt][nt][0] + b2f(old.x);
                v1 = acc[mt][nt][1] + b2f(old.y);
                v2 = acc[mt][nt][2] + b2f(old.z);
                v3 = acc[mt][nt][3] + b2f(old.w);
            }
            ushort4 st;
            st.x = f2b(v0); st.y = f2b(v1); st.z = f2b(v2); st.w = f2b(v3);
            *(ushort4*)p = st;
        }
    }
}

// ---------------------------------------------------------------------------
// Final: out = h + scale * (W2 x [dconv; h]), K=640. (round-3-verified)
__global__ __launch_bounds__(256) void k_final(const unsigned short* __restrict__ W2,
                                               const unsigned short* __restrict__ Cd,
                                               const unsigned short* __restrict__ Ch,
                                               const float* __restrict__ scale,
                                               float* __restrict__ out)
{
    __shared__ __align__(16) unsigned short As[128 * 32];
    __shared__ __align__(16) unsigned short Bs[32 * 128];
    const int tid = threadIdx.x;
    const int n0 = blockIdx.x * 128, m0 = blockIdx.y * 128;
    const int lane = tid & 63, w = tid >> 6;
    const int wm = w & 1, wn = w >> 1;
    const int quad = lane >> 4, nl = lane & 15;
    f32x4 acc[4][4];
    #pragma unroll
    for (int mt = 0; mt < 4; ++mt)
        #pragma unroll
        for (int nt = 0; nt < 4; ++nt)
            acc[mt][nt] = 0.f;

    for (int s = 0; s < 20; ++s) {
        __syncthreads();
        #pragma unroll
        for (int q = 0; q < 2; ++q) {
            int u = tid + q * 256;
            int m = u >> 2, qq = u & 3;
            gl_lds16(W2 + (size_t)(m0 + m) * 640 + s * 32 + qq * 8, &As[u * 8]);
        }
        const unsigned short* src = (s < 10) ? Cd : Ch;
        int gq = (s < 10) ? s * 4 : (s - 10) * 4;
        #pragma unroll
        for (int q = 0; q < 2; ++q) {
            int u = tid + q * 256;
            int kkb = u >> 7, nn = n0 + (u & 127);
            gl_lds16(src + ((size_t)(gq + kkb) * NTOT + nn) * 8, &Bs[u * 8]);
        }
        __syncthreads();
        bf16x8 a[4], bf[4];
        #pragma unroll
        for (int mt = 0; mt < 4; ++mt)
            a[mt] = *(const bf16x8*)&As[(wm * 64 + mt * 16 + nl) * 32 + quad * 8];
        #pragma unroll
        for (int nt = 0; nt < 4; ++nt)
            bf[nt] = *(const bf16x8*)&Bs[(quad * 128 + wn * 64 + nt * 16 + nl) * 8];
        #pragma unroll
        for (int mt = 0; mt < 4; ++mt)
            #pragma unroll
            for (int nt = 0; nt < 4; ++nt)
                acc[mt][nt] = __builtin_amdgcn_mfma_f32_16x16x32_bf16(a[mt], bf[nt], acc[mt][nt], 0, 0, 0);
    }

    float sc = scale[0];
    #pragma unroll
    for (int mt = 0; mt < 4; ++mt) {
        int o0 = m0 + wm * 64 + mt * 16 + quad * 4;
        if (o0 >= 320) continue;
        #pragma unroll
        for (int nt = 0; nt < 4; ++nt) {
            int n = n0 + wn * 64 + nt * 16 + nl;
            int b = n >> 12, px = n & 4095;
            ushort4 hv = *(const ushort4*)(Ch + ((size_t)(o0 >> 3) * NTOT + n) * 8 + (o0 & 7));
            size_t base = ((size_t)(b * 320 + o0)) * 4096 + px;
            out[base]            = b2f(hv.x) + sc * acc[mt][nt][0];
            out[base + 4096]     = b2f(hv.y) + sc * acc[mt][nt][1];
            out[base + 2 * 4096] = b2f(hv.z) + sc * acc[mt][nt][2];
            out[base + 3 * 4096] = b2f(hv.w) + sc * acc[mt][nt][3];
        }
    }
}

// ---------------------------------------------------------------------------
extern "C" void kernel_launch(void* const* d_in, const int* in_sizes, int n_in,
                              void* d_out, int out_size, void* d_ws, size_t ws_size,
                              hipStream_t stream)
{
    const float* x      = (const float*)d_in[0];
    const float* weight = (const float*)d_in[1];
    const float* bias   = (const float*)d_in[2];
    const float* w_down = (const float*)d_in[3];
    const float* w_up   = (const float*)d_in[4];
    const float* scale  = (const float*)d_in[5];
    const float* offset = (const float*)d_in[6];
    char* ws = (char*)d_ws;
    unsigned short* Cd = (unsigned short*)(ws + 0);
    unsigned short* Ch = (unsigned short*)(ws + 12582912);
    unsigned short* Wr = (unsigned short*)(ws + 25165824);
    unsigned short* W2 = (unsigned short*)(ws + 27377664);
    uint32_t*       oI = (uint32_t*)(ws + 27869184);
    float*          oWt = (float*)(ws + 28164096);
    unsigned short* Sp = (unsigned short*)(ws + 28753920);
    float* out = (float*)d_out;

    int cg;
    if (ws_size >= 123125760ull)      cg = 40;  // full K, register acc, no RMW
    else if (ws_size >= 47628288ull)  cg = 8;   // 5 passes/mode, bf16 RMW
    else                              cg = 4;   // 10 passes/mode (round-3-proven)
    const int passes = 40 / cg;
    const int s_steps = cg * 9 / 4;             // 90 / 18 / 9

    hipLaunchKernelGGL(k_off,   dim3(144), dim3(256), 0, stream, offset, oI, oWt);
    hipLaunchKernelGGL(k_packW, dim3(4320), dim3(256), 0, stream, weight, Wr);
    hipLaunchKernelGGL(k_comb2, dim3(5, 384), dim3(128), 0, stream, w_down, w_up, W2);

    for (int mode = 0; mode < 2; ++mode) {
        unsigned short* Cbuf = (mode == 0) ? Cd : Ch;
        for (int pass = 0; pass < passes; ++pass) {
            hipLaunchKernelGGL(k_gather, dim3(4, cg, 4), dim3(256), 0, stream,
                               x, oI, oWt, Sp, pass * cg * 8, mode);
            hipLaunchKernelGGL(k_gemm, dim3(128, 2), dim3(256), 0, stream,
                               Sp, Wr, Cbuf, bias, pass == 0 ? 1 : 0,
                               pass * cg * 72, s_steps);
        }
    }
    hipLaunchKernelGGL(k_final, dim3(128, 3), dim3(256), 0, stream,
                       W2, Cd, Ch, scale, out);
}

// Round 5
// 268.482 us; speedup vs baseline: 15.9654x; 1.3803x over previous
//
#include <hip/hip_runtime.h>
#include <stdint.h>

// B=4, C=O=320, H=W=64 -> HW=4096, N=16384/mode, fused N2=32768, K=2880 (M pad 384).
// K-permutation: kk = g*72 + k*8 + cl, c = g*8+cl (g<40, k<9, cl<8).
// S packed-8: elem(kk,n2) at ushort idx (kkb*nstride+n2)*8 + (kk&7), kkb=kk>>3.
// C packed-8: elem(o,n2) at (o>>3)*32768*8 + n2*8 + (o&7); n2<16384 = dconv, >= = h.
//
// ws layout (bytes):
//   Ccomb 0 .. 25,165,824 | Wr .. 27,377,664 | W2 .. 27,869,184
//   oI .. 28,164,096 | oWt .. 28,753,920 | Sp 28,753,920 ..
// Fused tier: Sp = 188,743,680 B -> total 217,497,600.
// Fallback (round-4-proven size): Sp = 94,371,840 -> total 123,125,760.

#define NTOT 16384

typedef __attribute__((ext_vector_type(4))) float f32x4;
typedef __attribute__((ext_vector_type(8))) short bf16x8;

typedef __attribute__((address_space(1))) const unsigned int uint_as1;
typedef __attribute__((address_space(3))) unsigned int uint_as3;

__device__ __forceinline__ void gl_lds16(const void* g, void* l) {
    __builtin_amdgcn_global_load_lds((uint_as1*)g, (uint_as3*)l, 16, 0, 0);
}

__device__ __forceinline__ unsigned short f2b(float f) {
    union { float f; uint32_t u; } v; v.f = f;
    uint32_t r = (v.u + 0x7FFFu + ((v.u >> 16) & 1u)) >> 16;
    return (unsigned short)r;
}
__device__ __forceinline__ float b2f(unsigned short h) {
    union { uint32_t u; float f; } v; v.u = ((uint32_t)h) << 16;
    return v.f;
}
__device__ __forceinline__ float b2f_lo(uint32_t u) {
    union { uint32_t u; float f; } v; v.u = u << 16;
    return v.f;
}
__device__ __forceinline__ float b2f_hi(uint32_t u) {
    union { uint32_t u; float f; } v; v.u = u & 0xFFFF0000u;
    return v.f;
}
__device__ __forceinline__ uint32_t pack2(float lo, float hi) {
    return (uint32_t)f2b(lo) | ((uint32_t)f2b(hi) << 16);
}

// ---------------------------------------------------------------------------
// Bilinear tables per (k, pixel) — verified rounds 1/3/4.
__global__ __launch_bounds__(256) void k_off(const float* __restrict__ off,
                                             uint32_t* __restrict__ oIdx,
                                             float* __restrict__ oW)
{
    int gid = blockIdx.x * 256 + threadIdx.x;
    if (gid >= 9 * 4096) return;
    int k = gid >> 12;
    int p = gid & 4095;
    int i = p >> 6, j = p & 63;
    float dy = off[(2 * k) * 4096 + p];
    float dx = off[(2 * k + 1) * 4096 + p];
    float py = (float)(i - 1 + k / 3) + dy;
    float px = (float)(j - 1 + k % 3) + dx;
    float fy = floorf(py), fx = floorf(px);
    float wy = py - fy, wx = px - fx;
    fy = fminf(fmaxf(fy, -100.f), 100.f);
    fx = fminf(fmaxf(fx, -100.f), 100.f);
    int y0 = (int)fy, x0 = (int)fx;
    float vy0 = (y0 >= 0 && y0 < 64) ? 1.f : 0.f;
    float vy1 = (y0 >= -1 && y0 < 63) ? 1.f : 0.f;
    float vx0 = (x0 >= 0 && x0 < 64) ? 1.f : 0.f;
    float vx1 = (x0 >= -1 && x0 < 63) ? 1.f : 0.f;
    float w00 = (1.f - wy) * (1.f - wx) * vy0 * vx0;
    float w01 = (1.f - wy) * wx * vy0 * vx1;
    float w10 = wy * (1.f - wx) * vy1 * vx0;
    float w11 = wy * wx * vy1 * vx1;
    int ya = min(max(y0, 0), 63), yb = min(max(y0 + 1, 0), 63);
    int xa = min(max(x0, 0), 63), xb = min(max(x0 + 1, 0), 63);
    oIdx[gid * 2 + 0] = (uint32_t)(ya * 64 + xa) | ((uint32_t)(ya * 64 + xb) << 16);
    oIdx[gid * 2 + 1] = (uint32_t)(yb * 64 + xa) | ((uint32_t)(yb * 64 + xb) << 16);
    oW[gid * 4 + 0] = w00;
    oW[gid * 4 + 1] = w01;
    oW[gid * 4 + 2] = w10;
    oW[gid * 4 + 3] = w11;
}

// ---------------------------------------------------------------------------
__global__ __launch_bounds__(256) void k_packW(const float* __restrict__ w,
                                               unsigned short* __restrict__ Wr)
{
    int gid = blockIdx.x * 256 + threadIdx.x;   // 384*2880
    if (gid >= 384 * 2880) return;
    int o = gid / 2880, kk = gid % 2880;
    int g = kk / 72, r = kk % 72, k = r >> 3, cl = r & 7, c = g * 8 + cl;
    float v = (o < 320) ? w[((size_t)o * 320 + c) * 9 + k] : 0.f;
    Wr[gid] = f2b(v);
}

// ---------------------------------------------------------------------------
__global__ __launch_bounds__(128) void k_comb2(const float* __restrict__ wd,
                                               const float* __restrict__ wu,
                                               unsigned short* __restrict__ W2)
{
    int kk2 = blockIdx.x * 128 + threadIdx.x;   // 640
    int o = blockIdx.y;                          // 384
    float acc = 0.f;
    if (o < 320) {
        for (int l = 0; l < 320; ++l)
            acc += wu[o * 320 + l] * wd[l * 640 + kk2];
    }
    W2[o * 640 + kk2] = f2b(acc);
}

// ---------------------------------------------------------------------------
// Gather: one block = (1024 px) x (8 channels of group gl) x batch b.
// LDS channel-interleaved pl32[px][pair]; one ds_read_b128 = all 8 channels.
// Writes S at n2 = n_off + b*4096 + px with row stride `nstride`.
__global__ __launch_bounds__(256) void k_gather(const float* __restrict__ x,
                                                const uint32_t* __restrict__ oIdx,
                                                const float* __restrict__ oW,
                                                unsigned short* __restrict__ Sp,
                                                int c_base, int mode,
                                                int nstride, int n_off)
{
    __shared__ __align__(16) uint32_t pl32[4096 * 4];   // 64 KB
    const int tid = threadIdx.x;
    const int split = blockIdx.x, gl = blockIdx.y, b = blockIdx.z;
    const int c0 = c_base + gl * 8;
    const float* xb = x + ((size_t)b * 320 + c0) * 4096;
    #pragma unroll 8
    for (int it = 0; it < 64; ++it) {
        int u = it * 256 + tid;
        int p = u & 3, px = u >> 2;
        float va = xb[(size_t)(2 * p) * 4096 + px];
        float vb = xb[(size_t)(2 * p + 1) * 4096 + px];
        pl32[px * 4 + p] = pack2(va, vb);
    }
    __syncthreads();

    for (int i = 0; i < 4; ++i) {
        int px = split * 1024 + i * 256 + tid;
        int n2 = n_off + b * 4096 + px;
        if (mode == 0) {
            #pragma unroll
            for (int k = 0; k < 9; ++k) {
                int gi = k * 4096 + px;
                uint32_t i0 = oIdx[gi * 2], i1 = oIdx[gi * 2 + 1];
                float4 w = *(const float4*)&oW[gi * 4];
                int4 t0 = *(const int4*)&pl32[(i0 & 0xFFFFu) * 4];
                int4 t1 = *(const int4*)&pl32[(i0 >> 16) * 4];
                int4 t2 = *(const int4*)&pl32[(i1 & 0xFFFFu) * 4];
                int4 t3 = *(const int4*)&pl32[(i1 >> 16) * 4];
                float ac[8];
                #pragma unroll
                for (int q = 0; q < 8; ++q) ac[q] = 0.f;
#define TAP(tv, wv) \
    ac[0] += wv * b2f_lo((uint32_t)tv.x); ac[1] += wv * b2f_hi((uint32_t)tv.x); \
    ac[2] += wv * b2f_lo((uint32_t)tv.y); ac[3] += wv * b2f_hi((uint32_t)tv.y); \
    ac[4] += wv * b2f_lo((uint32_t)tv.z); ac[5] += wv * b2f_hi((uint32_t)tv.z); \
    ac[6] += wv * b2f_lo((uint32_t)tv.w); ac[7] += wv * b2f_hi((uint32_t)tv.w);
                TAP(t0, w.x) TAP(t1, w.y) TAP(t2, w.z) TAP(t3, w.w)
#undef TAP
                int4 st;
                st.x = (int)pack2(ac[0], ac[1]);
                st.y = (int)pack2(ac[2], ac[3]);
                st.z = (int)pack2(ac[4], ac[5]);
                st.w = (int)pack2(ac[6], ac[7]);
                *(int4*)(Sp + ((size_t)(gl * 9 + k) * nstride + n2) * 8) = st;
            }
        } else {
            int row = px >> 6, col = px & 63;
            #pragma unroll
            for (int k = 0; k < 9; ++k) {
                int di = k / 3 - 1, dj = k % 3 - 1;
                bool ok = ((unsigned)(row + di) < 64u) && ((unsigned)(col + dj) < 64u);
                int idx = px + di * 64 + dj;
                int4 st = {0, 0, 0, 0};
                if (ok) st = *(const int4*)&pl32[idx * 4];
                *(int4*)(Sp + ((size_t)(gl * 9 + k) * nstride + n2) * 8) = st;
            }
        }
    }
}

// ---------------------------------------------------------------------------
// MFMA GEMM, full K=2880 in registers (90 BK=32 steps), no RMW.
// BM=BN=128, 4 waves 2x2 (wave tile 64x64, 4x4 accs) — m97 configuration.
// B read from Sp (stride s_nstride); C written packed-8 stride 32768 at c_off+n.
__global__ __launch_bounds__(256) void k_gemm(const unsigned short* __restrict__ Sp,
                                              const unsigned short* __restrict__ Wr,
                                              unsigned short* __restrict__ Cc,
                                              const float* __restrict__ bias,
                                              int s_nstride, int c_off)
{
    __shared__ __align__(16) unsigned short As[128 * 32];
    __shared__ __align__(16) unsigned short Bs[32 * 128];
    const int tid = threadIdx.x;
    const int n0 = blockIdx.x * 128, m0 = blockIdx.y * 128;
    const int lane = tid & 63, w = tid >> 6;
    const int wm = w & 1, wn = w >> 1;
    const int quad = lane >> 4, nl = lane & 15;
    f32x4 acc[4][4];
    #pragma unroll
    for (int mt = 0; mt < 4; ++mt)
        #pragma unroll
        for (int nt = 0; nt < 4; ++nt)
            acc[mt][nt] = 0.f;

    for (int s = 0; s < 90; ++s) {
        __syncthreads();
        #pragma unroll
        for (int q = 0; q < 2; ++q) {
            int u = tid + q * 256;
            int m = u >> 2, qq = u & 3;
            gl_lds16(Wr + (size_t)(m0 + m) * 2880 + s * 32 + qq * 8, &As[u * 8]);
        }
        #pragma unroll
        for (int q = 0; q < 2; ++q) {
            int u = tid + q * 256;
            int kkb = u >> 7, nn = n0 + (u & 127);
            gl_lds16(Sp + ((size_t)(s * 4 + kkb) * s_nstride + nn) * 8, &Bs[u * 8]);
        }
        __syncthreads();
        bf16x8 a[4], bf[4];
        #pragma unroll
        for (int mt = 0; mt < 4; ++mt)
            a[mt] = *(const bf16x8*)&As[(wm * 64 + mt * 16 + nl) * 32 + quad * 8];
        #pragma unroll
        for (int nt = 0; nt < 4; ++nt)
            bf[nt] = *(const bf16x8*)&Bs[(quad * 128 + wn * 64 + nt * 16 + nl) * 8];
        #pragma unroll
        for (int mt = 0; mt < 4; ++mt)
            #pragma unroll
            for (int nt = 0; nt < 4; ++nt)
                acc[mt][nt] = __builtin_amdgcn_mfma_f32_16x16x32_bf16(a[mt], bf[nt], acc[mt][nt], 0, 0, 0);
    }

    #pragma unroll
    for (int mt = 0; mt < 4; ++mt) {
        int o0 = m0 + wm * 64 + mt * 16 + quad * 4;
        float b0 = (o0 + 0 < 320) ? bias[o0 + 0] : 0.f;
        float b1 = (o0 + 1 < 320) ? bias[o0 + 1] : 0.f;
        float b2 = (o0 + 2 < 320) ? bias[o0 + 2] : 0.f;
        float b3 = (o0 + 3 < 320) ? bias[o0 + 3] : 0.f;
        #pragma unroll
        for (int nt = 0; nt < 4; ++nt) {
            int n2 = c_off + n0 + wn * 64 + nt * 16 + nl;
            unsigned short* p = Cc + ((size_t)(o0 >> 3) * 32768 + n2) * 8 + (o0 & 7);
            ushort4 st;
            st.x = f2b(acc[mt][nt][0] + b0);
            st.y = f2b(acc[mt][nt][1] + b1);
            st.z = f2b(acc[mt][nt][2] + b2);
            st.w = f2b(acc[mt][nt][3] + b3);
            *(ushort4*)p = st;
        }
    }
}

// ---------------------------------------------------------------------------
// Final: out = h + scale * (W2 x [dconv; h]), K=640; reads combined C
// (dconv at n2=n, h at n2=n+16384).
__global__ __launch_bounds__(256) void k_final(const unsigned short* __restrict__ W2,
                                               const unsigned short* __restrict__ Cc,
                                               const float* __restrict__ scale,
                                               float* __restrict__ out)
{
    __shared__ __align__(16) unsigned short As[128 * 32];
    __shared__ __align__(16) unsigned short Bs[32 * 128];
    const int tid = threadIdx.x;
    const int n0 = blockIdx.x * 128, m0 = blockIdx.y * 128;
    const int lane = tid & 63, w = tid >> 6;
    const int wm = w & 1, wn = w >> 1;
    const int quad = lane >> 4, nl = lane & 15;
    f32x4 acc[4][4];
    #pragma unroll
    for (int mt = 0; mt < 4; ++mt)
        #pragma unroll
        for (int nt = 0; nt < 4; ++nt)
            acc[mt][nt] = 0.f;

    for (int s = 0; s < 20; ++s) {
        __syncthreads();
        #pragma unroll
        for (int q = 0; q < 2; ++q) {
            int u = tid + q * 256;
            int m = u >> 2, qq = u & 3;
            gl_lds16(W2 + (size_t)(m0 + m) * 640 + s * 32 + qq * 8, &As[u * 8]);
        }
        int h_off = (s < 10) ? 0 : 16384;
        int gq = (s < 10) ? s * 4 : (s - 10) * 4;
        #pragma unroll
        for (int q = 0; q < 2; ++q) {
            int u = tid + q * 256;
            int kkb = u >> 7, nn = n0 + (u & 127);
            gl_lds16(Cc + ((size_t)(gq + kkb) * 32768 + h_off + nn) * 8, &Bs[u * 8]);
        }
        __syncthreads();
        bf16x8 a[4], bf[4];
        #pragma unroll
        for (int mt = 0; mt < 4; ++mt)
            a[mt] = *(const bf16x8*)&As[(wm * 64 + mt * 16 + nl) * 32 + quad * 8];
        #pragma unroll
        for (int nt = 0; nt < 4; ++nt)
            bf[nt] = *(const bf16x8*)&Bs[(quad * 128 + wn * 64 + nt * 16 + nl) * 8];
        #pragma unroll
        for (int mt = 0; mt < 4; ++mt)
            #pragma unroll
            for (int nt = 0; nt < 4; ++nt)
                acc[mt][nt] = __builtin_amdgcn_mfma_f32_16x16x32_bf16(a[mt], bf[nt], acc[mt][nt], 0, 0, 0);
    }

    float sc = scale[0];
    #pragma unroll
    for (int mt = 0; mt < 4; ++mt) {
        int o0 = m0 + wm * 64 + mt * 16 + quad * 4;
        if (o0 >= 320) continue;
        #pragma unroll
        for (int nt = 0; nt < 4; ++nt) {
            int n = n0 + wn * 64 + nt * 16 + nl;
            int b = n >> 12, px = n & 4095;
            ushort4 hv = *(const ushort4*)(Cc + ((size_t)(o0 >> 3) * 32768 + n + 16384) * 8 + (o0 & 7));
            size_t base = ((size_t)(b * 320 + o0)) * 4096 + px;
            out[base]            = b2f(hv.x) + sc * acc[mt][nt][0];
            out[base + 4096]     = b2f(hv.y) + sc * acc[mt][nt][1];
            out[base + 2 * 4096] = b2f(hv.z) + sc * acc[mt][nt][2];
            out[base + 3 * 4096] = b2f(hv.w) + sc * acc[mt][nt][3];
        }
    }
}

// ---------------------------------------------------------------------------
extern "C" void kernel_launch(void* const* d_in, const int* in_sizes, int n_in,
                              void* d_out, int out_size, void* d_ws, size_t ws_size,
                              hipStream_t stream)
{
    const float* x      = (const float*)d_in[0];
    const float* weight = (const float*)d_in[1];
    const float* bias   = (const float*)d_in[2];
    const float* w_down = (const float*)d_in[3];
    const float* w_up   = (const float*)d_in[4];
    const float* scale  = (const float*)d_in[5];
    const float* offset = (const float*)d_in[6];
    char* ws = (char*)d_ws;
    unsigned short* Cc  = (unsigned short*)(ws + 0);
    unsigned short* Wr  = (unsigned short*)(ws + 25165824);
    unsigned short* W2  = (unsigned short*)(ws + 27377664);
    uint32_t*       oI  = (uint32_t*)(ws + 27869184);
    float*          oWt = (float*)(ws + 28164096);
    unsigned short* Sp  = (unsigned short*)(ws + 28753920);
    float* out = (float*)d_out;

    hipLaunchKernelGGL(k_off,   dim3(144), dim3(256), 0, stream, offset, oI, oWt);
    hipLaunchKernelGGL(k_packW, dim3(4320), dim3(256), 0, stream, weight, Wr);
    hipLaunchKernelGGL(k_comb2, dim3(5, 384), dim3(128), 0, stream, w_down, w_up, W2);

    if (ws_size >= 217497600ull) {
        // Fused tier: both im2col halves live at once, one GEMM over N=32768.
        hipLaunchKernelGGL(k_gather, dim3(4, 40, 4), dim3(256), 0, stream,
                           x, oI, oWt, Sp, 0, 0, 32768, 0);
        hipLaunchKernelGGL(k_gather, dim3(4, 40, 4), dim3(256), 0, stream,
                           x, oI, oWt, Sp, 0, 1, 32768, 16384);
        hipLaunchKernelGGL(k_gemm, dim3(256, 3), dim3(256), 0, stream,
                           Sp, Wr, Cc, bias, 32768, 0);
    } else {
        // Fallback tier (123 MB, round-4-proven size): per-mode S, two GEMMs.
        for (int mode = 0; mode < 2; ++mode) {
            hipLaunchKernelGGL(k_gather, dim3(4, 40, 4), dim3(256), 0, stream,
                               x, oI, oWt, Sp, 0, mode, 16384, 0);
            hipLaunchKernelGGL(k_gemm, dim3(128, 3), dim3(256), 0, stream,
                               Sp, Wr, Cc, bias, 16384, mode * 16384);
        }
    }
    hipLaunchKernelGGL(k_final, dim3(128, 3), dim3(256), 0, stream,
                       W2, Cc, scale, out);
}

// Round 6
// 263.613 us; speedup vs baseline: 16.2602x; 1.0185x over previous
//
#include <hip/hip_runtime.h>
#include <stdint.h>

// B=4, C=O=320, H=W=64 -> HW=4096, fused N2=32768, K=2880 (M pad 384), Kf=640.
// K-permutation: kk = g*72 + k*8 + cl, c = g*8+cl (g<40, k<9, cl<8).
// S packed-8: elem(kk,n2) at ushort idx (kkb*nstride+n2)*8 + (kk&7), kkb=kk>>3.
// C packed-8: elem(o,n2) at (o>>3)*32768*8 + n2*8 + (o&7); n2<16384 dconv, >= h.
//
// ws layout (bytes):
//   Ccomb 0 .. 25,165,824 | Wr .. 27,377,664 | W2 .. 27,869,184
//   oI .. 28,164,096 | oWt .. 28,753,920 | Sp 28,753,920 ..
// Fused tier: Sp = 188,743,680 B -> total 217,497,600 (confirmed available r5).
// Fallback:   Sp =  94,371,840 B -> total 123,125,760 (round-4-proven).

#define NTOT 16384

typedef __attribute__((ext_vector_type(4))) float f32x4;
typedef __attribute__((ext_vector_type(8))) short bf16x8;

typedef __attribute__((address_space(1))) const unsigned int uint_as1;
typedef __attribute__((address_space(3))) unsigned int uint_as3;

__device__ __forceinline__ void gl_lds16(const void* g, void* l) {
    __builtin_amdgcn_global_load_lds((uint_as1*)g, (uint_as3*)l, 16, 0, 0);
}

__device__ __forceinline__ unsigned short f2b(float f) {
    union { float f; uint32_t u; } v; v.f = f;
    uint32_t r = (v.u + 0x7FFFu + ((v.u >> 16) & 1u)) >> 16;
    return (unsigned short)r;
}
__device__ __forceinline__ float b2f(unsigned short h) {
    union { uint32_t u; float f; } v; v.u = ((uint32_t)h) << 16;
    return v.f;
}
__device__ __forceinline__ float b2f_lo(uint32_t u) {
    union { uint32_t u; float f; } v; v.u = u << 16;
    return v.f;
}
__device__ __forceinline__ float b2f_hi(uint32_t u) {
    union { uint32_t u; float f; } v; v.u = u & 0xFFFF0000u;
    return v.f;
}
__device__ __forceinline__ uint32_t pack2(float lo, float hi) {
    return (uint32_t)f2b(lo) | ((uint32_t)f2b(hi) << 16);
}

// ---------------------------------------------------------------------------
// Fused prep: blocks [0,144) bilinear tables; [144,4464) pack Wr; [4464,5424)
// W2 = w_up @ w_down. All three verified in earlier rounds; only the grid
// partitioning is new.
__global__ __launch_bounds__(256) void k_prep(const float* __restrict__ off,
                                              const float* __restrict__ w,
                                              const float* __restrict__ wd,
                                              const float* __restrict__ wu,
                                              uint32_t* __restrict__ oIdx,
                                              float* __restrict__ oW,
                                              unsigned short* __restrict__ Wr,
                                              unsigned short* __restrict__ W2)
{
    const int bx = blockIdx.x, tid = threadIdx.x;
    if (bx < 144) {
        int gid = bx * 256 + tid;                    // 9*4096 exact
        int k = gid >> 12;
        int p = gid & 4095;
        int i = p >> 6, j = p & 63;
        float dy = off[(2 * k) * 4096 + p];
        float dx = off[(2 * k + 1) * 4096 + p];
        float py = (float)(i - 1 + k / 3) + dy;
        float px = (float)(j - 1 + k % 3) + dx;
        float fy = floorf(py), fx = floorf(px);
        float wy = py - fy, wx = px - fx;
        fy = fminf(fmaxf(fy, -100.f), 100.f);
        fx = fminf(fmaxf(fx, -100.f), 100.f);
        int y0 = (int)fy, x0 = (int)fx;
        float vy0 = (y0 >= 0 && y0 < 64) ? 1.f : 0.f;
        float vy1 = (y0 >= -1 && y0 < 63) ? 1.f : 0.f;
        float vx0 = (x0 >= 0 && x0 < 64) ? 1.f : 0.f;
        float vx1 = (x0 >= -1 && x0 < 63) ? 1.f : 0.f;
        float w00 = (1.f - wy) * (1.f - wx) * vy0 * vx0;
        float w01 = (1.f - wy) * wx * vy0 * vx1;
        float w10 = wy * (1.f - wx) * vy1 * vx0;
        float w11 = wy * wx * vy1 * vx1;
        int ya = min(max(y0, 0), 63), yb = min(max(y0 + 1, 0), 63);
        int xa = min(max(x0, 0), 63), xb = min(max(x0 + 1, 0), 63);
        oIdx[gid * 2 + 0] = (uint32_t)(ya * 64 + xa) | ((uint32_t)(ya * 64 + xb) << 16);
        oIdx[gid * 2 + 1] = (uint32_t)(yb * 64 + xa) | ((uint32_t)(yb * 64 + xb) << 16);
        oW[gid * 4 + 0] = w00;
        oW[gid * 4 + 1] = w01;
        oW[gid * 4 + 2] = w10;
        oW[gid * 4 + 3] = w11;
    } else if (bx < 144 + 4320) {
        int gid = (bx - 144) * 256 + tid;            // 384*2880 exact
        int o = gid / 2880, kk = gid % 2880;
        int g = kk / 72, r = kk % 72, k = r >> 3, cl = r & 7, c = g * 8 + cl;
        float v = (o < 320) ? w[((size_t)o * 320 + c) * 9 + k] : 0.f;
        Wr[gid] = f2b(v);
    } else {
        int gid = (bx - 4464) * 256 + tid;           // 384*640 exact
        int o = gid / 640, kk2 = gid % 640;
        float acc = 0.f;
        if (o < 320) {
            for (int l = 0; l < 320; ++l)
                acc += wu[o * 320 + l] * wd[l * 640 + kk2];
        }
        W2[gid] = f2b(acc);
    }
}

// ---------------------------------------------------------------------------
// Fused gather: stage 8 bf16 x-planes (channel-interleaved pairs) once, emit
// BOTH im2col halves. mode: 0 = bilinear only, 1 = shift only, 2 = both.
__global__ __launch_bounds__(256) void k_gather(const float* __restrict__ x,
                                                const uint32_t* __restrict__ oIdx,
                                                const float* __restrict__ oW,
                                                unsigned short* __restrict__ Sp,
                                                int nstride, int d_off, int h_off,
                                                int mode)
{
    __shared__ __align__(16) uint32_t pl32[4096 * 4];   // 64 KB
    const int tid = threadIdx.x;
    const int split = blockIdx.x, gl = blockIdx.y, b = blockIdx.z;
    const float* xb = x + ((size_t)b * 320 + gl * 8) * 4096;
    // stage: lane l writes LDS dword base*4+l -> 64 consecutive dwords/wave
    // (2-way bank aliasing = free).
    #pragma unroll 8
    for (int it = 0; it < 64; ++it) {
        int u = it * 256 + tid;
        int p = u & 3, px = u >> 2;
        float va = xb[(size_t)(2 * p) * 4096 + px];
        float vb = xb[(size_t)(2 * p + 1) * 4096 + px];
        pl32[px * 4 + p] = pack2(va, vb);
    }
    __syncthreads();

    for (int i = 0; i < 4; ++i) {
        int px = split * 1024 + i * 256 + tid;
        int nb = b * 4096 + px;
        if (mode != 0) {                              // shift half (h conv)
            int row = px >> 6, col = px & 63;
            #pragma unroll
            for (int k = 0; k < 9; ++k) {
                int di = k / 3 - 1, dj = k % 3 - 1;
                bool ok = ((unsigned)(row + di) < 64u) && ((unsigned)(col + dj) < 64u);
                int idx = px + di * 64 + dj;
                int4 st = {0, 0, 0, 0};
                if (ok) st = *(const int4*)&pl32[idx * 4];
                *(int4*)(Sp + ((size_t)(gl * 9 + k) * nstride + h_off + nb) * 8) = st;
            }
        }
        if (mode != 1) {                              // bilinear half (dconv)
            #pragma unroll
            for (int k = 0; k < 9; ++k) {
                int gi = k * 4096 + px;
                uint32_t i0 = oIdx[gi * 2], i1 = oIdx[gi * 2 + 1];
                float4 w = *(const float4*)&oW[gi * 4];
                int4 t0 = *(const int4*)&pl32[(i0 & 0xFFFFu) * 4];
                int4 t1 = *(const int4*)&pl32[(i0 >> 16) * 4];
                int4 t2 = *(const int4*)&pl32[(i1 & 0xFFFFu) * 4];
                int4 t3 = *(const int4*)&pl32[(i1 >> 16) * 4];
                float ac[8];
                #pragma unroll
                for (int q = 0; q < 8; ++q) ac[q] = 0.f;
#define TAP(tv, wv) \
    ac[0] += wv * b2f_lo((uint32_t)tv.x); ac[1] += wv * b2f_hi((uint32_t)tv.x); \
    ac[2] += wv * b2f_lo((uint32_t)tv.y); ac[3] += wv * b2f_hi((uint32_t)tv.y); \
    ac[4] += wv * b2f_lo((uint32_t)tv.z); ac[5] += wv * b2f_hi((uint32_t)tv.z); \
    ac[6] += wv * b2f_lo((uint32_t)tv.w); ac[7] += wv * b2f_hi((uint32_t)tv.w);
                TAP(t0, w.x) TAP(t1, w.y) TAP(t2, w.z) TAP(t3, w.w)
#undef TAP
                int4 st;
                st.x = (int)pack2(ac[0], ac[1]);
                st.y = (int)pack2(ac[2], ac[3]);
                st.z = (int)pack2(ac[4], ac[5]);
                st.w = (int)pack2(ac[6], ac[7]);
                *(int4*)(Sp + ((size_t)(gl * 9 + k) * nstride + d_off + nb) * 8) = st;
            }
        }
    }
}

// ---------------------------------------------------------------------------
// MFMA GEMM, full K=2880 in registers (90 BK=32 steps), no RMW.
// BM=BN=128, 4 waves 2x2 (wave tile 64x64) — round-5-verified at 811 TF.
__global__ __launch_bounds__(256) void k_gemm(const unsigned short* __restrict__ Sp,
                                              const unsigned short* __restrict__ Wr,
                                              unsigned short* __restrict__ Cc,
                                              const float* __restrict__ bias,
                                              int s_nstride, int c_off)
{
    __shared__ __align__(16) unsigned short As[128 * 32];
    __shared__ __align__(16) unsigned short Bs[32 * 128];
    const int tid = threadIdx.x;
    const int n0 = blockIdx.x * 128, m0 = blockIdx.y * 128;
    const int lane = tid & 63, w = tid >> 6;
    const int wm = w & 1, wn = w >> 1;
    const int quad = lane >> 4, nl = lane & 15;
    f32x4 acc[4][4];
    #pragma unroll
    for (int mt = 0; mt < 4; ++mt)
        #pragma unroll
        for (int nt = 0; nt < 4; ++nt)
            acc[mt][nt] = 0.f;

    for (int s = 0; s < 90; ++s) {
        __syncthreads();
        #pragma unroll
        for (int q = 0; q < 2; ++q) {
            int u = tid + q * 256;
            int m = u >> 2, qq = u & 3;
            gl_lds16(Wr + (size_t)(m0 + m) * 2880 + s * 32 + qq * 8, &As[u * 8]);
        }
        #pragma unroll
        for (int q = 0; q < 2; ++q) {
            int u = tid + q * 256;
            int kkb = u >> 7, nn = n0 + (u & 127);
            gl_lds16(Sp + ((size_t)(s * 4 + kkb) * s_nstride + nn) * 8, &Bs[u * 8]);
        }
        __syncthreads();
        bf16x8 a[4], bf[4];
        #pragma unroll
        for (int mt = 0; mt < 4; ++mt)
            a[mt] = *(const bf16x8*)&As[(wm * 64 + mt * 16 + nl) * 32 + quad * 8];
        #pragma unroll
        for (int nt = 0; nt < 4; ++nt)
            bf[nt] = *(const bf16x8*)&Bs[(quad * 128 + wn * 64 + nt * 16 + nl) * 8];
        #pragma unroll
        for (int mt = 0; mt < 4; ++mt)
            #pragma unroll
            for (int nt = 0; nt < 4; ++nt)
                acc[mt][nt] = __builtin_amdgcn_mfma_f32_16x16x32_bf16(a[mt], bf[nt], acc[mt][nt], 0, 0, 0);
    }

    #pragma unroll
    for (int mt = 0; mt < 4; ++mt) {
        int o0 = m0 + wm * 64 + mt * 16 + quad * 4;
        float b0 = (o0 + 0 < 320) ? bias[o0 + 0] : 0.f;
        float b1 = (o0 + 1 < 320) ? bias[o0 + 1] : 0.f;
        float b2 = (o0 + 2 < 320) ? bias[o0 + 2] : 0.f;
        float b3 = (o0 + 3 < 320) ? bias[o0 + 3] : 0.f;
        #pragma unroll
        for (int nt = 0; nt < 4; ++nt) {
            int n2 = c_off + n0 + wn * 64 + nt * 16 + nl;
            unsigned short* p = Cc + ((size_t)(o0 >> 3) * 32768 + n2) * 8 + (o0 & 7);
            ushort4 st;
            st.x = f2b(acc[mt][nt][0] + b0);
            st.y = f2b(acc[mt][nt][1] + b1);
            st.z = f2b(acc[mt][nt][2] + b2);
            st.w = f2b(acc[mt][nt][3] + b3);
            *(ushort4*)p = st;
        }
    }
}

// ---------------------------------------------------------------------------
// Final: out = h + scale * (W2 x [dconv; h]), K=640 (round-5-verified).
__global__ __launch_bounds__(256) void k_final(const unsigned short* __restrict__ W2,
                                               const unsigned short* __restrict__ Cc,
                                               const float* __restrict__ scale,
                                               float* __restrict__ out)
{
    __shared__ __align__(16) unsigned short As[128 * 32];
    __shared__ __align__(16) unsigned short Bs[32 * 128];
    const int tid = threadIdx.x;
    const int n0 = blockIdx.x * 128, m0 = blockIdx.y * 128;
    const int lane = tid & 63, w = tid >> 6;
    const int wm = w & 1, wn = w >> 1;
    const int quad = lane >> 4, nl = lane & 15;
    f32x4 acc[4][4];
    #pragma unroll
    for (int mt = 0; mt < 4; ++mt)
        #pragma unroll
        for (int nt = 0; nt < 4; ++nt)
            acc[mt][nt] = 0.f;

    for (int s = 0; s < 20; ++s) {
        __syncthreads();
        #pragma unroll
        for (int q = 0; q < 2; ++q) {
            int u = tid + q * 256;
            int m = u >> 2, qq = u & 3;
            gl_lds16(W2 + (size_t)(m0 + m) * 640 + s * 32 + qq * 8, &As[u * 8]);
        }
        int h_off = (s < 10) ? 0 : 16384;
        int gq = (s < 10) ? s * 4 : (s - 10) * 4;
        #pragma unroll
        for (int q = 0; q < 2; ++q) {
            int u = tid + q * 256;
            int kkb = u >> 7, nn = n0 + (u & 127);
            gl_lds16(Cc + ((size_t)(gq + kkb) * 32768 + h_off + nn) * 8, &Bs[u * 8]);
        }
        __syncthreads();
        bf16x8 a[4], bf[4];
        #pragma unroll
        for (int mt = 0; mt < 4; ++mt)
            a[mt] = *(const bf16x8*)&As[(wm * 64 + mt * 16 + nl) * 32 + quad * 8];
        #pragma unroll
        for (int nt = 0; nt < 4; ++nt)
            bf[nt] = *(const bf16x8*)&Bs[(quad * 128 + wn * 64 + nt * 16 + nl) * 8];
        #pragma unroll
        for (int mt = 0; mt < 4; ++mt)
            #pragma unroll
            for (int nt = 0; nt < 4; ++nt)
                acc[mt][nt] = __builtin_amdgcn_mfma_f32_16x16x32_bf16(a[mt], bf[nt], acc[mt][nt], 0, 0, 0);
    }

    float sc = scale[0];
    #pragma unroll
    for (int mt = 0; mt < 4; ++mt) {
        int o0 = m0 + wm * 64 + mt * 16 + quad * 4;
        if (o0 >= 320) continue;
        #pragma unroll
        for (int nt = 0; nt < 4; ++nt) {
            int n = n0 + wn * 64 + nt * 16 + nl;
            int b = n >> 12, px = n & 4095;
            ushort4 hv = *(const ushort4*)(Cc + ((size_t)(o0 >> 3) * 32768 + n + 16384) * 8 + (o0 & 7));
            size_t base = ((size_t)(b * 320 + o0)) * 4096 + px;
            out[base]            = b2f(hv.x) + sc * acc[mt][nt][0];
            out[base + 4096]     = b2f(hv.y) + sc * acc[mt][nt][1];
            out[base + 2 * 4096] = b2f(hv.z) + sc * acc[mt][nt][2];
            out[base + 3 * 4096] = b2f(hv.w) + sc * acc[mt][nt][3];
        }
    }
}

// ---------------------------------------------------------------------------
extern "C" void kernel_launch(void* const* d_in, const int* in_sizes, int n_in,
                              void* d_out, int out_size, void* d_ws, size_t ws_size,
                              hipStream_t stream)
{
    const float* x      = (const float*)d_in[0];
    const float* weight = (const float*)d_in[1];
    const float* bias   = (const float*)d_in[2];
    const float* w_down = (const float*)d_in[3];
    const float* w_up   = (const float*)d_in[4];
    const float* scale  = (const float*)d_in[5];
    const float* offset = (const float*)d_in[6];
    char* ws = (char*)d_ws;
    unsigned short* Cc  = (unsigned short*)(ws + 0);
    unsigned short* Wr  = (unsigned short*)(ws + 25165824);
    unsigned short* W2  = (unsigned short*)(ws + 27377664);
    uint32_t*       oI  = (uint32_t*)(ws + 27869184);
    float*          oWt = (float*)(ws + 28164096);
    unsigned short* Sp  = (unsigned short*)(ws + 28753920);
    float* out = (float*)d_out;

    hipLaunchKernelGGL(k_prep, dim3(5424), dim3(256), 0, stream,
                       offset, weight, w_down, w_up, oI, oWt, Wr, W2);

    if (ws_size >= 217497600ull) {
        // Fused tier: one gather emits both halves, one GEMM over N=32768.
        hipLaunchKernelGGL(k_gather, dim3(4, 40, 4), dim3(256), 0, stream,
                           x, oI, oWt, Sp, 32768, 0, 16384, 2);
        hipLaunchKernelGGL(k_gemm, dim3(256, 3), dim3(256), 0, stream,
                           Sp, Wr, Cc, bias, 32768, 0);
    } else {
        // Fallback tier (123 MB): per-mode S, two GEMMs (round-5-proven).
        for (int mode = 0; mode < 2; ++mode) {
            hipLaunchKernelGGL(k_gather, dim3(4, 40, 4), dim3(256), 0, stream,
                               x, oI, oWt, Sp, 16384, 0, 0, mode);
            hipLaunchKernelGGL(k_gemm, dim3(128, 3), dim3(256), 0, stream,
                               Sp, Wr, Cc, bias, 16384, mode * 16384);
        }
    }
    hipLaunchKernelGGL(k_final, dim3(128, 3), dim3(256), 0, stream,
                       W2, Cc, scale, out);
}

// Round 7
// 251.714 us; speedup vs baseline: 17.0289x; 1.0473x over previous
//
#include <hip/hip_runtime.h>
#include <stdint.h>

// B=4, C=O=320, H=W=64 -> HW=4096, N2=32768 (dconv n<16384, h n>=16384),
// K=2880 (M pad 384), Kf=640.
// K-permutation: kk = g*72 + k*8 + cl, c = g*8+cl (g<40, k<9, cl<8); kkb=kk>>3=g*9+k.
// S packed-8 (dconv only): elem(kk,n) at ushort idx (kkb*16384+n)*8 + (kk&7).
// Xp (padded x, h half): [g][b][py 66][px 66][cl 8] bf16; interior = x, halo = 0.
// C packed-8: elem(o,n2) at (o>>3)*32768*8 + n2*8 + (o&7).
//
// ws layout (bytes):
//   Cc 0..25,165,824 | Wr ..27,377,664 | W2 ..27,869,184 | oI ..28,164,096
//   oWt ..28,753,920 | hoffG ..28,758,016 (360 ints + pad)
//   Xp ..39,909,376 (11,151,360) | Sd ..134,281,216 (94,371,840)

typedef __attribute__((ext_vector_type(4))) float f32x4;
typedef __attribute__((ext_vector_type(8))) short bf16x8;

typedef __attribute__((address_space(1))) const unsigned int uint_as1;
typedef __attribute__((address_space(3))) unsigned int uint_as3;

__device__ __forceinline__ void gl_lds16(const void* g, void* l) {
    __builtin_amdgcn_global_load_lds((uint_as1*)g, (uint_as3*)l, 16, 0, 0);
}

__device__ __forceinline__ unsigned short f2b(float f) {
    union { float f; uint32_t u; } v; v.f = f;
    uint32_t r = (v.u + 0x7FFFu + ((v.u >> 16) & 1u)) >> 16;
    return (unsigned short)r;
}
__device__ __forceinline__ float b2f(unsigned short h) {
    union { uint32_t u; float f; } v; v.u = ((uint32_t)h) << 16;
    return v.f;
}
__device__ __forceinline__ float b2f_lo(uint32_t u) {
    union { uint32_t u; float f; } v; v.u = u << 16;
    return v.f;
}
__device__ __forceinline__ float b2f_hi(uint32_t u) {
    union { uint32_t u; float f; } v; v.u = u & 0xFFFF0000u;
    return v.f;
}
__device__ __forceinline__ uint32_t pack2(float lo, float hi) {
    return (uint32_t)f2b(lo) | ((uint32_t)f2b(hi) << 16);
}

// ---------------------------------------------------------------------------
// Fused prep. Partitions: [0,144) bilinear tables; [144,4464) Wr pack;
// [4464,5424) W2; [5424,5426) hoffG (360 shift offsets); [5426,6107) zero Xp.
__global__ __launch_bounds__(256) void k_prep(const float* __restrict__ off,
                                              const float* __restrict__ w,
                                              const float* __restrict__ wd,
                                              const float* __restrict__ wu,
                                              uint32_t* __restrict__ oIdx,
                                              float* __restrict__ oW,
                                              unsigned short* __restrict__ Wr,
                                              unsigned short* __restrict__ W2,
                                              int* __restrict__ hoffG,
                                              unsigned short* __restrict__ Xp)
{
    const int bx = blockIdx.x, tid = threadIdx.x;
    if (bx < 144) {
        int gid = bx * 256 + tid;                    // 9*4096 exact
        int k = gid >> 12;
        int p = gid & 4095;
        int i = p >> 6, j = p & 63;
        float dy = off[(2 * k) * 4096 + p];
        float dx = off[(2 * k + 1) * 4096 + p];
        float py = (float)(i - 1 + k / 3) + dy;
        float px = (float)(j - 1 + k % 3) + dx;
        float fy = floorf(py), fx = floorf(px);
        float wy = py - fy, wx = px - fx;
        fy = fminf(fmaxf(fy, -100.f), 100.f);
        fx = fminf(fmaxf(fx, -100.f), 100.f);
        int y0 = (int)fy, x0 = (int)fx;
        float vy0 = (y0 >= 0 && y0 < 64) ? 1.f : 0.f;
        float vy1 = (y0 >= -1 && y0 < 63) ? 1.f : 0.f;
        float vx0 = (x0 >= 0 && x0 < 64) ? 1.f : 0.f;
        float vx1 = (x0 >= -1 && x0 < 63) ? 1.f : 0.f;
        float w00 = (1.f - wy) * (1.f - wx) * vy0 * vx0;
        float w01 = (1.f - wy) * wx * vy0 * vx1;
        float w10 = wy * (1.f - wx) * vy1 * vx0;
        float w11 = wy * wx * vy1 * vx1;
        int ya = min(max(y0, 0), 63), yb = min(max(y0 + 1, 0), 63);
        int xa = min(max(x0, 0), 63), xb = min(max(x0 + 1, 0), 63);
        oIdx[gid * 2 + 0] = (uint32_t)(ya * 64 + xa) | ((uint32_t)(ya * 64 + xb) << 16);
        oIdx[gid * 2 + 1] = (uint32_t)(yb * 64 + xa) | ((uint32_t)(yb * 64 + xb) << 16);
        oW[gid * 4 + 0] = w00;
        oW[gid * 4 + 1] = w01;
        oW[gid * 4 + 2] = w10;
        oW[gid * 4 + 3] = w11;
    } else if (bx < 4464) {
        int gid = (bx - 144) * 256 + tid;            // 384*2880 exact
        int o = gid / 2880, kk = gid % 2880;
        int g = kk / 72, r = kk % 72, k = r >> 3, cl = r & 7, c = g * 8 + cl;
        float v = (o < 320) ? w[((size_t)o * 320 + c) * 9 + k] : 0.f;
        Wr[gid] = f2b(v);
    } else if (bx < 5424) {
        int gid = (bx - 4464) * 256 + tid;           // 384*640 exact
        int o = gid / 640, kk2 = gid % 640;
        float acc = 0.f;
        if (o < 320) {
            for (int l = 0; l < 320; ++l)
                acc += wu[o * 320 + l] * wd[l * 640 + kk2];
        }
        W2[gid] = f2b(acc);
    } else if (bx < 5426) {
        int kkb = (bx - 5424) * 256 + tid;           // 360 entries
        if (kkb < 360) {
            int g = kkb / 9, k = kkb % 9;
            hoffG[kkb] = (g * 17424 + (k / 3) * 66 + (k % 3)) * 8; // ushort units
        }
    } else {
        // zero Xp: 696,960 int4 units
        int bz = bx - 5426;                          // 681 blocks
        #pragma unroll
        for (int j = 0; j < 4; ++j) {
            int u = bz * 1024 + j * 256 + tid;
            if (u < 696960) {
                int4 z = {0, 0, 0, 0};
                ((int4*)Xp)[u] = z;
            }
        }
    }
}

// ---------------------------------------------------------------------------
// Gather: stage 8 bf16 x-planes (channel-interleaved pairs) once; emit the
// bilinear im2col half (9 stores/px) + the padded pack-8 x copy (1 store/px).
__global__ __launch_bounds__(256) void k_gather(const float* __restrict__ x,
                                                const uint32_t* __restrict__ oIdx,
                                                const float* __restrict__ oW,
                                                unsigned short* __restrict__ Sd,
                                                unsigned short* __restrict__ Xp)
{
    __shared__ __align__(16) uint32_t pl32[4096 * 4];   // 64 KB
    const int tid = threadIdx.x;
    const int split = blockIdx.x, gl = blockIdx.y, b = blockIdx.z;
    const float* xb = x + ((size_t)b * 320 + gl * 8) * 4096;
    #pragma unroll 8
    for (int it = 0; it < 64; ++it) {
        int u = it * 256 + tid;
        int p = u & 3, px = u >> 2;
        float va = xb[(size_t)(2 * p) * 4096 + px];
        float vb = xb[(size_t)(2 * p + 1) * 4096 + px];
        pl32[px * 4 + p] = pack2(va, vb);
    }
    __syncthreads();

    for (int i = 0; i < 4; ++i) {
        int px = split * 1024 + i * 256 + tid;
        int nb = b * 4096 + px;
        int row = px >> 6, col = px & 63;
        // padded pack-8 copy (interior cell (row+1, col+1))
        {
            int4 st = *(const int4*)&pl32[px * 4];
            size_t a = ((size_t)(gl * 4 + b) * 4356 + (row + 1) * 66 + (col + 1)) * 8;
            *(int4*)(Xp + a) = st;
        }
        // bilinear im2col (dconv half)
        #pragma unroll
        for (int k = 0; k < 9; ++k) {
            int gi = k * 4096 + px;
            uint32_t i0 = oIdx[gi * 2], i1 = oIdx[gi * 2 + 1];
            float4 w = *(const float4*)&oW[gi * 4];
            int4 t0 = *(const int4*)&pl32[(i0 & 0xFFFFu) * 4];
            int4 t1 = *(const int4*)&pl32[(i0 >> 16) * 4];
            int4 t2 = *(const int4*)&pl32[(i1 & 0xFFFFu) * 4];
            int4 t3 = *(const int4*)&pl32[(i1 >> 16) * 4];
            float ac[8];
            #pragma unroll
            for (int q = 0; q < 8; ++q) ac[q] = 0.f;
#define TAP(tv, wv) \
    ac[0] += wv * b2f_lo((uint32_t)tv.x); ac[1] += wv * b2f_hi((uint32_t)tv.x); \
    ac[2] += wv * b2f_lo((uint32_t)tv.y); ac[3] += wv * b2f_hi((uint32_t)tv.y); \
    ac[4] += wv * b2f_lo((uint32_t)tv.z); ac[5] += wv * b2f_hi((uint32_t)tv.z); \
    ac[6] += wv * b2f_lo((uint32_t)tv.w); ac[7] += wv * b2f_hi((uint32_t)tv.w);
            TAP(t0, w.x) TAP(t1, w.y) TAP(t2, w.z) TAP(t3, w.w)
#undef TAP
            int4 st;
            st.x = (int)pack2(ac[0], ac[1]);
            st.y = (int)pack2(ac[2], ac[3]);
            st.z = (int)pack2(ac[4], ac[5]);
            st.w = (int)pack2(ac[6], ac[7]);
            *(int4*)(Sd + ((size_t)(gl * 9 + k) * 16384 + nb) * 8) = st;
        }
    }
}

// ---------------------------------------------------------------------------
// MFMA GEMM, full K=2880 (90 BK=32 steps), fp32 register acc, no RMW.
// BM=BN=128, 4 waves 2x2 — round-5/6-verified structure. B source:
// n0<16384 -> materialized Sd; n0>=16384 -> implicit shifts into padded Xp.
__global__ __launch_bounds__(256) void k_gemm(const unsigned short* __restrict__ Sd,
                                              const unsigned short* __restrict__ Xp,
                                              const int* __restrict__ hoffG,
                                              const unsigned short* __restrict__ Wr,
                                              unsigned short* __restrict__ Cc,
                                              const float* __restrict__ bias)
{
    __shared__ __align__(16) unsigned short As[128 * 32];
    __shared__ __align__(16) unsigned short Bs[32 * 128];
    const int tid = threadIdx.x;
    const int n0 = blockIdx.x * 128, m0 = blockIdx.y * 128;
    const int lane = tid & 63, w = tid >> 6;
    const int wm = w & 1, wn = w >> 1;
    const int quad = lane >> 4, nl = lane & 15;
    const bool hHalf = (n0 >= 16384);
    // per-thread invariant base addresses for the implicit-Xp path (q=0,1)
    int xbase[2];
    #pragma unroll
    for (int q = 0; q < 2; ++q) {
        int u = tid + q * 256;
        int nn = (n0 - 16384) + (u & 127);
        int b = nn >> 12, px = nn & 4095;
        xbase[q] = (b * 4356 + (px >> 6) * 66 + (px & 63)) * 8;
    }
    f32x4 acc[4][4];
    #pragma unroll
    for (int mt = 0; mt < 4; ++mt)
        #pragma unroll
        for (int nt = 0; nt < 4; ++nt)
            acc[mt][nt] = 0.f;

    for (int s = 0; s < 90; ++s) {
        __syncthreads();
        #pragma unroll
        for (int q = 0; q < 2; ++q) {
            int u = tid + q * 256;
            int m = u >> 2, qq = u & 3;
            gl_lds16(Wr + (size_t)(m0 + m) * 2880 + s * 32 + qq * 8, &As[u * 8]);
        }
        if (!hHalf) {
            #pragma unroll
            for (int q = 0; q < 2; ++q) {
                int u = tid + q * 256;
                int kkb = u >> 7, nn = n0 + (u & 127);
                gl_lds16(Sd + ((size_t)(s * 4 + kkb) * 16384 + nn) * 8, &Bs[u * 8]);
            }
        } else {
            #pragma unroll
            for (int q = 0; q < 2; ++q) {
                int u = tid + q * 256;
                int kkb = s * 4 + (u >> 7);          // wave-uniform
                int off = hoffG[__builtin_amdgcn_readfirstlane(kkb)];
                gl_lds16(Xp + (size_t)(xbase[q] + off), &Bs[u * 8]);
            }
        }
        __syncthreads();
        bf16x8 a[4], bf[4];
        #pragma unroll
        for (int mt = 0; mt < 4; ++mt)
            a[mt] = *(const bf16x8*)&As[(wm * 64 + mt * 16 + nl) * 32 + quad * 8];
        #pragma unroll
        for (int nt = 0; nt < 4; ++nt)
            bf[nt] = *(const bf16x8*)&Bs[(quad * 128 + wn * 64 + nt * 16 + nl) * 8];
        #pragma unroll
        for (int mt = 0; mt < 4; ++mt)
            #pragma unroll
            for (int nt = 0; nt < 4; ++nt)
                acc[mt][nt] = __builtin_amdgcn_mfma_f32_16x16x32_bf16(a[mt], bf[nt], acc[mt][nt], 0, 0, 0);
    }

    #pragma unroll
    for (int mt = 0; mt < 4; ++mt) {
        int o0 = m0 + wm * 64 + mt * 16 + quad * 4;
        float b0 = (o0 + 0 < 320) ? bias[o0 + 0] : 0.f;
        float b1 = (o0 + 1 < 320) ? bias[o0 + 1] : 0.f;
        float b2 = (o0 + 2 < 320) ? bias[o0 + 2] : 0.f;
        float b3 = (o0 + 3 < 320) ? bias[o0 + 3] : 0.f;
        #pragma unroll
        for (int nt = 0; nt < 4; ++nt) {
            int n2 = n0 + wn * 64 + nt * 16 + nl;
            unsigned short* p = Cc + ((size_t)(o0 >> 3) * 32768 + n2) * 8 + (o0 & 7);
            ushort4 st;
            st.x = f2b(acc[mt][nt][0] + b0);
            st.y = f2b(acc[mt][nt][1] + b1);
            st.z = f2b(acc[mt][nt][2] + b2);
            st.w = f2b(acc[mt][nt][3] + b3);
            *(ushort4*)p = st;
        }
    }
}

// ---------------------------------------------------------------------------
// Final: out = h + scale * (W2 x [dconv; h]), K=640 (rounds-5/6-verified).
__global__ __launch_bounds__(256) void k_final(const unsigned short* __restrict__ W2,
                                               const unsigned short* __restrict__ Cc,
                                               const float* __restrict__ scale,
                                               float* __restrict__ out)
{
    __shared__ __align__(16) unsigned short As[128 * 32];
    __shared__ __align__(16) unsigned short Bs[32 * 128];
    const int tid = threadIdx.x;
    const int n0 = blockIdx.x * 128, m0 = blockIdx.y * 128;
    const int lane = tid & 63, w = tid >> 6;
    const int wm = w & 1, wn = w >> 1;
    const int quad = lane >> 4, nl = lane & 15;
    f32x4 acc[4][4];
    #pragma unroll
    for (int mt = 0; mt < 4; ++mt)
        #pragma unroll
        for (int nt = 0; nt < 4; ++nt)
            acc[mt][nt] = 0.f;

    for (int s = 0; s < 20; ++s) {
        __syncthreads();
        #pragma unroll
        for (int q = 0; q < 2; ++q) {
            int u = tid + q * 256;
            int m = u >> 2, qq = u & 3;
            gl_lds16(W2 + (size_t)(m0 + m) * 640 + s * 32 + qq * 8, &As[u * 8]);
        }
        int h_off = (s < 10) ? 0 : 16384;
        int gq = (s < 10) ? s * 4 : (s - 10) * 4;
        #pragma unroll
        for (int q = 0; q < 2; ++q) {
            int u = tid + q * 256;
            int kkb = u >> 7, nn = n0 + (u & 127);
            gl_lds16(Cc + ((size_t)(gq + kkb) * 32768 + h_off + nn) * 8, &Bs[u * 8]);
        }
        __syncthreads();
        bf16x8 a[4], bf[4];
        #pragma unroll
        for (int mt = 0; mt < 4; ++mt)
            a[mt] = *(const bf16x8*)&As[(wm * 64 + mt * 16 + nl) * 32 + quad * 8];
        #pragma unroll
        for (int nt = 0; nt < 4; ++nt)
            bf[nt] = *(const bf16x8*)&Bs[(quad * 128 + wn * 64 + nt * 16 + nl) * 8];
        #pragma unroll
        for (int mt = 0; mt < 4; ++mt)
            #pragma unroll
            for (int nt = 0; nt < 4; ++nt)
                acc[mt][nt] = __builtin_amdgcn_mfma_f32_16x16x32_bf16(a[mt], bf[nt], acc[mt][nt], 0, 0, 0);
    }

    float sc = scale[0];
    #pragma unroll
    for (int mt = 0; mt < 4; ++mt) {
        int o0 = m0 + wm * 64 + mt * 16 + quad * 4;
        if (o0 >= 320) continue;
        #pragma unroll
        for (int nt = 0; nt < 4; ++nt) {
            int n = n0 + wn * 64 + nt * 16 + nl;
            int b = n >> 12, px = n & 4095;
            ushort4 hv = *(const ushort4*)(Cc + ((size_t)(o0 >> 3) * 32768 + n + 16384) * 8 + (o0 & 7));
            size_t base = ((size_t)(b * 320 + o0)) * 4096 + px;
            out[base]            = b2f(hv.x) + sc * acc[mt][nt][0];
            out[base + 4096]     = b2f(hv.y) + sc * acc[mt][nt][1];
            out[base + 2 * 4096] = b2f(hv.z) + sc * acc[mt][nt][2];
            out[base + 3 * 4096] = b2f(hv.w) + sc * acc[mt][nt][3];
        }
    }
}

// ---------------------------------------------------------------------------
extern "C" void kernel_launch(void* const* d_in, const int* in_sizes, int n_in,
                              void* d_out, int out_size, void* d_ws, size_t ws_size,
                              hipStream_t stream)
{
    const float* x      = (const float*)d_in[0];
    const float* weight = (const float*)d_in[1];
    const float* bias   = (const float*)d_in[2];
    const float* w_down = (const float*)d_in[3];
    const float* w_up   = (const float*)d_in[4];
    const float* scale  = (const float*)d_in[5];
    const float* offset = (const float*)d_in[6];
    char* ws = (char*)d_ws;
    unsigned short* Cc    = (unsigned short*)(ws + 0);
    unsigned short* Wr    = (unsigned short*)(ws + 25165824);
    unsigned short* W2    = (unsigned short*)(ws + 27377664);
    uint32_t*       oI    = (uint32_t*)(ws + 27869184);
    float*          oWt   = (float*)(ws + 28164096);
    int*            hoffG = (int*)(ws + 28753920);
    unsigned short* Xp    = (unsigned short*)(ws + 28758016);
    unsigned short* Sd    = (unsigned short*)(ws + 39909376);
    float* out = (float*)d_out;

    hipLaunchKernelGGL(k_prep, dim3(6107), dim3(256), 0, stream,
                       offset, weight, w_down, w_up, oI, oWt, Wr, W2, hoffG, Xp);
    hipLaunchKernelGGL(k_gather, dim3(4, 40, 4), dim3(256), 0, stream,
                       x, oI, oWt, Sd, Xp);
    hipLaunchKernelGGL(k_gemm, dim3(256, 3), dim3(256), 0, stream,
                       Sd, Xp, hoffG, Wr, Cc, bias);
    hipLaunchKernelGGL(k_final, dim3(128, 3), dim3(256), 0, stream,
                       W2, Cc, scale, out);
}

// Round 8
// 243.911 us; speedup vs baseline: 17.5737x; 1.0320x over previous
//
#include <hip/hip_runtime.h>
#include <stdint.h>

// B=4, C=O=320, H=W=64 -> HW=4096, N2=32768 (dconv n<16384, h n>=16384),
// K=2880 (M pad 384), Kf=640.
// K-permutation: kk = g*72 + k*8 + cl, c = g*8+cl (g<40, k<9, cl<8); kkb=kk>>3=g*9+k.
// S packed-8 (dconv only): elem(kk,n) at ushort idx (kkb*16384+n)*8 + (kk&7).
// Xp (padded x, h half): [g][b][py 66][px 66][cl 8] bf16; interior = x, halo = 0.
// C packed-8: elem(o,n2) at (o>>3)*32768*8 + n2*8 + (o&7).
//
// ws layout (bytes):
//   Cc 0..25,165,824 | Wr ..27,377,664 | W2 ..27,869,184 | oI ..28,164,096
//   oWt ..28,753,920 | hoffG ..28,758,016 (360 ints + pad)
//   Xp ..39,909,376 (11,151,360) | Sd ..134,281,216 (94,371,840)

typedef __attribute__((ext_vector_type(4))) float f32x4;
typedef __attribute__((ext_vector_type(8))) short bf16x8;

typedef __attribute__((address_space(1))) const unsigned int uint_as1;
typedef __attribute__((address_space(3))) unsigned int uint_as3;

__device__ __forceinline__ void gl_lds16(const void* g, void* l) {
    __builtin_amdgcn_global_load_lds((uint_as1*)g, (uint_as3*)l, 16, 0, 0);
}

__device__ __forceinline__ unsigned short f2b(float f) {
    union { float f; uint32_t u; } v; v.f = f;
    uint32_t r = (v.u + 0x7FFFu + ((v.u >> 16) & 1u)) >> 16;
    return (unsigned short)r;
}
__device__ __forceinline__ float b2f(unsigned short h) {
    union { uint32_t u; float f; } v; v.u = ((uint32_t)h) << 16;
    return v.f;
}
__device__ __forceinline__ float b2f_lo(uint32_t u) {
    union { uint32_t u; float f; } v; v.u = u << 16;
    return v.f;
}
__device__ __forceinline__ float b2f_hi(uint32_t u) {
    union { uint32_t u; float f; } v; v.u = u & 0xFFFF0000u;
    return v.f;
}
__device__ __forceinline__ uint32_t pack2(float lo, float hi) {
    return (uint32_t)f2b(lo) | ((uint32_t)f2b(hi) << 16);
}

// ---------------------------------------------------------------------------
// Fused prep. Partitions: [0,144) bilinear tables; [144,4464) Wr pack;
// [4464,5424) W2; [5424,5426) hoffG; [5426,6107) zero Xp. (round-7-verified)
__global__ __launch_bounds__(256) void k_prep(const float* __restrict__ off,
                                              const float* __restrict__ w,
                                              const float* __restrict__ wd,
                                              const float* __restrict__ wu,
                                              uint32_t* __restrict__ oIdx,
                                              float* __restrict__ oW,
                                              unsigned short* __restrict__ Wr,
                                              unsigned short* __restrict__ W2,
                                              int* __restrict__ hoffG,
                                              unsigned short* __restrict__ Xp)
{
    const int bx = blockIdx.x, tid = threadIdx.x;
    if (bx < 144) {
        int gid = bx * 256 + tid;                    // 9*4096 exact
        int k = gid >> 12;
        int p = gid & 4095;
        int i = p >> 6, j = p & 63;
        float dy = off[(2 * k) * 4096 + p];
        float dx = off[(2 * k + 1) * 4096 + p];
        float py = (float)(i - 1 + k / 3) + dy;
        float px = (float)(j - 1 + k % 3) + dx;
        float fy = floorf(py), fx = floorf(px);
        float wy = py - fy, wx = px - fx;
        fy = fminf(fmaxf(fy, -100.f), 100.f);
        fx = fminf(fmaxf(fx, -100.f), 100.f);
        int y0 = (int)fy, x0 = (int)fx;
        float vy0 = (y0 >= 0 && y0 < 64) ? 1.f : 0.f;
        float vy1 = (y0 >= -1 && y0 < 63) ? 1.f : 0.f;
        float vx0 = (x0 >= 0 && x0 < 64) ? 1.f : 0.f;
        float vx1 = (x0 >= -1 && x0 < 63) ? 1.f : 0.f;
        float w00 = (1.f - wy) * (1.f - wx) * vy0 * vx0;
        float w01 = (1.f - wy) * wx * vy0 * vx1;
        float w10 = wy * (1.f - wx) * vy1 * vx0;
        float w11 = wy * wx * vy1 * vx1;
        int ya = min(max(y0, 0), 63), yb = min(max(y0 + 1, 0), 63);
        int xa = min(max(x0, 0), 63), xb = min(max(x0 + 1, 0), 63);
        oIdx[gid * 2 + 0] = (uint32_t)(ya * 64 + xa) | ((uint32_t)(ya * 64 + xb) << 16);
        oIdx[gid * 2 + 1] = (uint32_t)(yb * 64 + xa) | ((uint32_t)(yb * 64 + xb) << 16);
        oW[gid * 4 + 0] = w00;
        oW[gid * 4 + 1] = w01;
        oW[gid * 4 + 2] = w10;
        oW[gid * 4 + 3] = w11;
    } else if (bx < 4464) {
        int gid = (bx - 144) * 256 + tid;            // 384*2880 exact
        int o = gid / 2880, kk = gid % 2880;
        int g = kk / 72, r = kk % 72, k = r >> 3, cl = r & 7, c = g * 8 + cl;
        float v = (o < 320) ? w[((size_t)o * 320 + c) * 9 + k] : 0.f;
        Wr[gid] = f2b(v);
    } else if (bx < 5424) {
        int gid = (bx - 4464) * 256 + tid;           // 384*640 exact
        int o = gid / 640, kk2 = gid % 640;
        float acc = 0.f;
        if (o < 320) {
            for (int l = 0; l < 320; ++l)
                acc += wu[o * 320 + l] * wd[l * 640 + kk2];
        }
        W2[gid] = f2b(acc);
    } else if (bx < 5426) {
        int kkb = (bx - 5424) * 256 + tid;           // 360 entries
        if (kkb < 360) {
            int g = kkb / 9, k = kkb % 9;
            hoffG[kkb] = (g * 17424 + (k / 3) * 66 + (k % 3)) * 8; // ushort units
        }
    } else {
        // zero Xp: 696,960 int4 units
        int bz = bx - 5426;                          // 681 blocks
        #pragma unroll
        for (int j = 0; j < 4; ++j) {
            int u = bz * 1024 + j * 256 + tid;
            if (u < 696960) {
                int4 z = {0, 0, 0, 0};
                ((int4*)Xp)[u] = z;
            }
        }
    }
}

// ---------------------------------------------------------------------------
// Gather: stage 8 bf16 x-planes once; emit bilinear im2col (9 stores/px) +
// padded pack-8 x copy (1 store/px). (round-7-verified)
__global__ __launch_bounds__(256) void k_gather(const float* __restrict__ x,
                                                const uint32_t* __restrict__ oIdx,
                                                const float* __restrict__ oW,
                                                unsigned short* __restrict__ Sd,
                                                unsigned short* __restrict__ Xp)
{
    __shared__ __align__(16) uint32_t pl32[4096 * 4];   // 64 KB
    const int tid = threadIdx.x;
    const int split = blockIdx.x, gl = blockIdx.y, b = blockIdx.z;
    const float* xb = x + ((size_t)b * 320 + gl * 8) * 4096;
    #pragma unroll 8
    for (int it = 0; it < 64; ++it) {
        int u = it * 256 + tid;
        int p = u & 3, px = u >> 2;
        float va = xb[(size_t)(2 * p) * 4096 + px];
        float vb = xb[(size_t)(2 * p + 1) * 4096 + px];
        pl32[px * 4 + p] = pack2(va, vb);
    }
    __syncthreads();

    for (int i = 0; i < 4; ++i) {
        int px = split * 1024 + i * 256 + tid;
        int nb = b * 4096 + px;
        int row = px >> 6, col = px & 63;
        {
            int4 st = *(const int4*)&pl32[px * 4];
            size_t a = ((size_t)(gl * 4 + b) * 4356 + (row + 1) * 66 + (col + 1)) * 8;
            *(int4*)(Xp + a) = st;
        }
        #pragma unroll
        for (int k = 0; k < 9; ++k) {
            int gi = k * 4096 + px;
            uint32_t i0 = oIdx[gi * 2], i1 = oIdx[gi * 2 + 1];
            float4 w = *(const float4*)&oW[gi * 4];
            int4 t0 = *(const int4*)&pl32[(i0 & 0xFFFFu) * 4];
            int4 t1 = *(const int4*)&pl32[(i0 >> 16) * 4];
            int4 t2 = *(const int4*)&pl32[(i1 & 0xFFFFu) * 4];
            int4 t3 = *(const int4*)&pl32[(i1 >> 16) * 4];
            float ac[8];
            #pragma unroll
            for (int q = 0; q < 8; ++q) ac[q] = 0.f;
#define TAP(tv, wv) \
    ac[0] += wv * b2f_lo((uint32_t)tv.x); ac[1] += wv * b2f_hi((uint32_t)tv.x); \
    ac[2] += wv * b2f_lo((uint32_t)tv.y); ac[3] += wv * b2f_hi((uint32_t)tv.y); \
    ac[4] += wv * b2f_lo((uint32_t)tv.z); ac[5] += wv * b2f_hi((uint32_t)tv.z); \
    ac[6] += wv * b2f_lo((uint32_t)tv.w); ac[7] += wv * b2f_hi((uint32_t)tv.w);
            TAP(t0, w.x) TAP(t1, w.y) TAP(t2, w.z) TAP(t3, w.w)
#undef TAP
            int4 st;
            st.x = (int)pack2(ac[0], ac[1]);
            st.y = (int)pack2(ac[2], ac[3]);
            st.z = (int)pack2(ac[4], ac[5]);
            st.w = (int)pack2(ac[6], ac[7]);
            *(int4*)(Sd + ((size_t)(gl * 9 + k) * 16384 + nb) * 8) = st;
        }
    }
}

// ---------------------------------------------------------------------------
// MFMA GEMM, full K=2880 as 45 BK=64 steps (2 K=32 sub-chunks each), fp32
// register acc. BM=BN=128, 4 waves 2x2. All-pad wave tiles (rows>=320) skip
// fragment loads + MFMA + C-write (frees matrix pipe for co-resident blocks).
__global__ __launch_bounds__(256) void k_gemm(const unsigned short* __restrict__ Sd,
                                              const unsigned short* __restrict__ Xp,
                                              const int* __restrict__ hoffG,
                                              const unsigned short* __restrict__ Wr,
                                              unsigned short* __restrict__ Cc,
                                              const float* __restrict__ bias)
{
    __shared__ __align__(16) unsigned short As[128 * 64];   // 16 KB
    __shared__ __align__(16) unsigned short Bs[64 * 128];   // 16 KB
    const int tid = threadIdx.x;
    const int n0 = blockIdx.x * 128, m0 = blockIdx.y * 128;
    const int lane = tid & 63, w = tid >> 6;
    const int wm = w & 1, wn = w >> 1;
    const int quad = lane >> 4, nl = lane & 15;
    const bool hHalf = (n0 >= 16384);
    const bool mActive = (m0 + wm * 64) < 320;
    // per-thread invariant Xp base (n depends only on tid&127)
    int xbase;
    {
        int nn = (n0 - 16384) + (tid & 127);
        int b = nn >> 12, px = nn & 4095;
        xbase = (b * 4356 + (px >> 6) * 66 + (px & 63)) * 8;
    }
    f32x4 acc[4][4];
    #pragma unroll
    for (int mt = 0; mt < 4; ++mt)
        #pragma unroll
        for (int nt = 0; nt < 4; ++nt)
            acc[mt][nt] = 0.f;

    for (int s = 0; s < 45; ++s) {
        __syncthreads();
        #pragma unroll
        for (int q = 0; q < 4; ++q) {
            int u = tid + q * 256;
            int m = u >> 3, kq = u & 7;
            gl_lds16(Wr + (size_t)(m0 + m) * 2880 + s * 64 + kq * 8, &As[u * 8]);
        }
        if (!hHalf) {
            #pragma unroll
            for (int q = 0; q < 4; ++q) {
                int u = tid + q * 256;
                int row = u >> 7, nn = n0 + (u & 127);
                gl_lds16(Sd + ((size_t)(s * 8 + row) * 16384 + nn) * 8, &Bs[u * 8]);
            }
        } else {
            #pragma unroll
            for (int q = 0; q < 4; ++q) {
                int u = tid + q * 256;
                int kkb = s * 8 + (u >> 7);          // wave-uniform
                int off = hoffG[__builtin_amdgcn_readfirstlane(kkb)];
                gl_lds16(Xp + (size_t)(xbase + off), &Bs[u * 8]);
            }
        }
        __syncthreads();
        if (mActive) {
            #pragma unroll
            for (int kc = 0; kc < 2; ++kc) {
                bf16x8 a[4], bf[4];
                #pragma unroll
                for (int mt = 0; mt < 4; ++mt)
                    a[mt] = *(const bf16x8*)&As[(wm * 64 + mt * 16 + nl) * 64 + kc * 32 + quad * 8];
                #pragma unroll
                for (int nt = 0; nt < 4; ++nt)
                    bf[nt] = *(const bf16x8*)&Bs[(kc * 4 + quad) * 1024 + (wn * 64 + nt * 16 + nl) * 8];
                #pragma unroll
                for (int mt = 0; mt < 4; ++mt)
                    #pragma unroll
                    for (int nt = 0; nt < 4; ++nt)
                        acc[mt][nt] = __builtin_amdgcn_mfma_f32_16x16x32_bf16(a[mt], bf[nt], acc[mt][nt], 0, 0, 0);
            }
        }
    }

    if (mActive) {
        #pragma unroll
        for (int mt = 0; mt < 4; ++mt) {
            int o0 = m0 + wm * 64 + mt * 16 + quad * 4;
            float b0 = (o0 + 0 < 320) ? bias[o0 + 0] : 0.f;
            float b1 = (o0 + 1 < 320) ? bias[o0 + 1] : 0.f;
            float b2 = (o0 + 2 < 320) ? bias[o0 + 2] : 0.f;
            float b3 = (o0 + 3 < 320) ? bias[o0 + 3] : 0.f;
            #pragma unroll
            for (int nt = 0; nt < 4; ++nt) {
                int n2 = n0 + wn * 64 + nt * 16 + nl;
                unsigned short* p = Cc + ((size_t)(o0 >> 3) * 32768 + n2) * 8 + (o0 & 7);
                ushort4 st;
                st.x = f2b(acc[mt][nt][0] + b0);
                st.y = f2b(acc[mt][nt][1] + b1);
                st.z = f2b(acc[mt][nt][2] + b2);
                st.w = f2b(acc[mt][nt][3] + b3);
                *(ushort4*)p = st;
            }
        }
    }
}

// ---------------------------------------------------------------------------
// Final: out = h + scale * (W2 x [dconv; h]), K=640 as 10 BK=64 steps.
__global__ __launch_bounds__(256) void k_final(const unsigned short* __restrict__ W2,
                                               const unsigned short* __restrict__ Cc,
                                               const float* __restrict__ scale,
                                               float* __restrict__ out)
{
    __shared__ __align__(16) unsigned short As[128 * 64];
    __shared__ __align__(16) unsigned short Bs[64 * 128];
    const int tid = threadIdx.x;
    const int n0 = blockIdx.x * 128, m0 = blockIdx.y * 128;
    const int lane = tid & 63, w = tid >> 6;
    const int wm = w & 1, wn = w >> 1;
    const int quad = lane >> 4, nl = lane & 15;
    const bool mActive = (m0 + wm * 64) < 320;
    f32x4 acc[4][4];
    #pragma unroll
    for (int mt = 0; mt < 4; ++mt)
        #pragma unroll
        for (int nt = 0; nt < 4; ++nt)
            acc[mt][nt] = 0.f;

    for (int s = 0; s < 10; ++s) {
        __syncthreads();
        #pragma unroll
        for (int q = 0; q < 4; ++q) {
            int u = tid + q * 256;
            int m = u >> 3, kq = u & 7;
            gl_lds16(W2 + (size_t)(m0 + m) * 640 + s * 64 + kq * 8, &As[u * 8]);
        }
        int h_off = (s < 5) ? 0 : 16384;
        int gq = (s < 5) ? s * 8 : (s - 5) * 8;
        #pragma unroll
        for (int q = 0; q < 4; ++q) {
            int u = tid + q * 256;
            int row = u >> 7, nn = n0 + (u & 127);
            gl_lds16(Cc + ((size_t)(gq + row) * 32768 + h_off + nn) * 8, &Bs[u * 8]);
        }
        __syncthreads();
        if (mActive) {
            #pragma unroll
            for (int kc = 0; kc < 2; ++kc) {
                bf16x8 a[4], bf[4];
                #pragma unroll
                for (int mt = 0; mt < 4; ++mt)
                    a[mt] = *(const bf16x8*)&As[(wm * 64 + mt * 16 + nl) * 64 + kc * 32 + quad * 8];
                #pragma unroll
                for (int nt = 0; nt < 4; ++nt)
                    bf[nt] = *(const bf16x8*)&Bs[(kc * 4 + quad) * 1024 + (wn * 64 + nt * 16 + nl) * 8];
                #pragma unroll
                for (int mt = 0; mt < 4; ++mt)
                    #pragma unroll
                    for (int nt = 0; nt < 4; ++nt)
                        acc[mt][nt] = __builtin_amdgcn_mfma_f32_16x16x32_bf16(a[mt], bf[nt], acc[mt][nt], 0, 0, 0);
            }
        }
    }

    float sc = scale[0];
    if (mActive) {
        #pragma unroll
        for (int mt = 0; mt < 4; ++mt) {
            int o0 = m0 + wm * 64 + mt * 16 + quad * 4;
            if (o0 >= 320) continue;
            #pragma unroll
            for (int nt = 0; nt < 4; ++nt) {
                int n = n0 + wn * 64 + nt * 16 + nl;
                int b = n >> 12, px = n & 4095;
                ushort4 hv = *(const ushort4*)(Cc + ((size_t)(o0 >> 3) * 32768 + n + 16384) * 8 + (o0 & 7));
                size_t base = ((size_t)(b * 320 + o0)) * 4096 + px;
                out[base]            = b2f(hv.x) + sc * acc[mt][nt][0];
                out[base + 4096]     = b2f(hv.y) + sc * acc[mt][nt][1];
                out[base + 2 * 4096] = b2f(hv.z) + sc * acc[mt][nt][2];
                out[base + 3 * 4096] = b2f(hv.w) + sc * acc[mt][nt][3];
            }
        }
    }
}

// ---------------------------------------------------------------------------
extern "C" void kernel_launch(void* const* d_in, const int* in_sizes, int n_in,
                              void* d_out, int out_size, void* d_ws, size_t ws_size,
                              hipStream_t stream)
{
    const float* x      = (const float*)d_in[0];
    const float* weight = (const float*)d_in[1];
    const float* bias   = (const float*)d_in[2];
    const float* w_down = (const float*)d_in[3];
    const float* w_up   = (const float*)d_in[4];
    const float* scale  = (const float*)d_in[5];
    const float* offset = (const float*)d_in[6];
    char* ws = (char*)d_ws;
    unsigned short* Cc    = (unsigned short*)(ws + 0);
    unsigned short* Wr    = (unsigned short*)(ws + 25165824);
    unsigned short* W2    = (unsigned short*)(ws + 27377664);
    uint32_t*       oI    = (uint32_t*)(ws + 27869184);
    float*          oWt   = (float*)(ws + 28164096);
    int*            hoffG = (int*)(ws + 28753920);
    unsigned short* Xp    = (unsigned short*)(ws + 28758016);
    unsigned short* Sd    = (unsigned short*)(ws + 39909376);
    float* out = (float*)d_out;

    hipLaunchKernelGGL(k_prep, dim3(6107), dim3(256), 0, stream,
                       offset, weight, w_down, w_up, oI, oWt, Wr, W2, hoffG, Xp);
    hipLaunchKernelGGL(k_gather, dim3(4, 40, 4), dim3(256), 0, stream,
                       x, oI, oWt, Sd, Xp);
    hipLaunchKernelGGL(k_gemm, dim3(256, 3), dim3(256), 0, stream,
                       Sd, Xp, hoffG, Wr, Cc, bias);
    hipLaunchKernelGGL(k_final, dim3(128, 3), dim3(256), 0, stream,
                       W2, Cc, scale, out);
}